// Round 7
// baseline (1861.878 us; speedup 1.0000x reference)
//
#include <hip/hip_runtime.h>

#define NATOMS 300000
#define NCOLS 8
#define VOCABSZ 4096
#define DCOL 32
#define HIDDIM 256
#define NBONDS 320000
#define NGRAPHS 6000
#define NSTEPS 3

constexpr int MP = 300032;             // atoms padded to multiple of 128
constexpr int MTILES128 = MP / 128;    // 2344 gemm blocks
constexpr int HSTR = 2 * HIDDIM;       // interleaved h row: [hi256|lo256]
constexpr int XSTR = 2 * DCOL;         // interleaved x row: [hi32|lo32]
constexpr int ECAP = 32;               // CSR slots/atom; P(deg>32) < 1e-20

typedef _Float16 f16;
typedef _Float16 f16x8 __attribute__((ext_vector_type(8)));
typedef float f32x4 __attribute__((ext_vector_type(4)));

constexpr float LO_SCALE = 2048.0f;      // 2^11: keeps lo parts fp16-normal
constexpr float INV_LO   = 1.0f / 2048.0f;

__device__ __forceinline__ void split2(float x, f16& h, f16& l) {
    h = (f16)x;
    l = (f16)((x - (float)h) * LO_SCALE);
}

// 16B-unit XOR swizzle (r10: measured ZERO bank conflicts). Involution in q.
__device__ __forceinline__ int swz(int row, int q) {
    return (row * 4 + (q ^ ((row >> 1) & 3))) * 8;
}

// Async global->LDS DMA, 16B per lane per wave-instruction.
__device__ __forceinline__ void dma16(const f16* g, f16* l) {
    __builtin_amdgcn_global_load_lds(
        (const __attribute__((address_space(1))) uint32_t*)g,
        (__attribute__((address_space(3))) uint32_t*)l, 16, 0, 0);
}

// ---------------------------------------------------------------------------
static void* g_pool = nullptr;
__attribute__((constructor)) static void alloc_pool() {
    void* p = nullptr;
    if (hipMalloc(&p, (size_t)1024 * 1024 * 1024) == hipSuccess) {
        hipMemset(p, 0, (size_t)1024 * 1024 * 1024);
        g_pool = p;
    }
}

// ---------------------------------------------------------------------------
__global__ void fill_kernel(float* out, float v, int n) {
    int i = blockIdx.x * blockDim.x + threadIdx.x;
    if (i < n) out[i] = v;
}

// ---------------------------------------------------------------------------
// Bucketed-CSR build: slot = atomicAdd(cnt[dst]); csr[dst*ECAP+slot] = src.
__global__ void csr_build_kernel(const int* __restrict__ bf, int* __restrict__ cnt,
                                 int* __restrict__ csr) {
    int e = blockIdx.x * blockDim.x + threadIdx.x;
    if (e >= 2 * NBONDS) return;
    int src, dst;
    if (e < NBONDS) { src = bf[e * 3 + 0]; dst = bf[e * 3 + 1]; }
    else { int i = e - NBONDS; src = bf[i * 3 + 1]; dst = bf[i * 3 + 0]; }
    int slot = atomicAdd(&cnt[dst], 1);
    if (slot < ECAP) csr[dst * ECAP + slot] = src;
}

// ---------------------------------------------------------------------------
__global__ void wsplit_kernel(const float* __restrict__ W, f16* __restrict__ Wh,
                              f16* __restrict__ Wl, int n) {
    int i = blockIdx.x * blockDim.x + threadIdx.x;
    if (i >= n) return;
    split2(W[i], Wh[i], Wl[i]);
}

__global__ void bsum_kernel(const float* __restrict__ a, const float* __restrict__ b,
                            float* __restrict__ o) {
    int i = threadIdx.x;
    o[i] = a[i] + b[i];
}

// ---------------------------------------------------------------------------
// Embedding -> interleaved x rows [hi32|lo32].
__global__ void embed_kernel(const int* __restrict__ af, const float* __restrict__ emb,
                             f16* __restrict__ x) {
    int gid = blockIdx.x * blockDim.x + threadIdx.x;
    int i = gid >> 5, k = gid & 31;
    if (i >= NATOMS) return;
    float s = 0.0f;
#pragma unroll
    for (int c = 0; c < NCOLS; c++) {
        int v = af[i * NCOLS + c];
        int idx = v & (VOCABSZ - 1);
        if (v >= 999999999) idx = 0;
        s += emb[((size_t)c * VOCABSZ + idx) * DCOL + k];
    }
    f16 hi, lo;
    split2(s, hi, lo);
    x[(size_t)i * XSTR + k] = hi;
    x[(size_t)i * XSTR + DCOL + k] = lo;
}

// ---------------------------------------------------------------------------
// Aggregation over bucketed CSR (R6, proven: no nxt-chase, MLP 2-4).
__global__ void agg_kernel(const f16* __restrict__ H, f16* __restrict__ G,
                           const int* __restrict__ cnt, const int* __restrict__ csr) {
    int wid = (blockIdx.x * blockDim.x + threadIdx.x) >> 6;
    int lane = threadIdx.x & 63;
    if (wid >= NATOMS) return;
    float a0 = 0.f, a1 = 0.f, a2 = 0.f, a3 = 0.f,
          a4 = 0.f, a5 = 0.f, a6 = 0.f, a7 = 0.f;
    const int degr = cnt[wid];
    const int deg = degr < ECAP ? degr : ECAP;
    const int* eb = csr + (size_t)wid * ECAP;
    int j = 0;
    for (; j + 2 <= deg; j += 2) {
        const int2 ss = *(const int2*)(eb + j);          // 8B-aligned (j even)
        const f16x8 v0 = *(const f16x8*)(H + (size_t)ss.x * HSTR + lane * 8);
        const f16x8 v1 = *(const f16x8*)(H + (size_t)ss.y * HSTR + lane * 8);
        a0 += (float)v0[0] + (float)v1[0];
        a1 += (float)v0[1] + (float)v1[1];
        a2 += (float)v0[2] + (float)v1[2];
        a3 += (float)v0[3] + (float)v1[3];
        a4 += (float)v0[4] + (float)v1[4];
        a5 += (float)v0[5] + (float)v1[5];
        a6 += (float)v0[6] + (float)v1[6];
        a7 += (float)v0[7] + (float)v1[7];
    }
    if (j < deg) {
        const int s0 = eb[j];
        const f16x8 v = *(const f16x8*)(H + (size_t)s0 * HSTR + lane * 8);
        a0 += (float)v[0]; a1 += (float)v[1]; a2 += (float)v[2]; a3 += (float)v[3];
        a4 += (float)v[4]; a5 += (float)v[5]; a6 += (float)v[6]; a7 += (float)v[7];
    }
    const bool isLo = lane >= 32;
    if (isLo) {
        a0 *= INV_LO; a1 *= INV_LO; a2 *= INV_LO; a3 *= INV_LO;
        a4 *= INV_LO; a5 *= INV_LO; a6 *= INV_LO; a7 *= INV_LO;
    }
    float s0 = a0 + __shfl_xor(a0, 32, 64);
    float s1 = a1 + __shfl_xor(a1, 32, 64);
    float s2 = a2 + __shfl_xor(a2, 32, 64);
    float s3 = a3 + __shfl_xor(a3, 32, 64);
    float s4 = a4 + __shfl_xor(a4, 32, 64);
    float s5 = a5 + __shfl_xor(a5, 32, 64);
    float s6 = a6 + __shfl_xor(a6, 32, 64);
    float s7 = a7 + __shfl_xor(a7, 32, 64);
    f16x8 o;
#define EMIT(J, S)                                                    \
    {                                                                 \
        const f16 hv = (f16)(S);                                      \
        o[J] = isLo ? (f16)(((S) - (float)hv) * LO_SCALE) : hv;       \
    }
    EMIT(0, s0) EMIT(1, s1) EMIT(2, s2) EMIT(3, s3)
    EMIT(4, s4) EMIT(5, s5) EMIT(6, s6) EMIT(7, s7)
#undef EMIT
    *(f16x8*)(G + (size_t)wid * HSTR + lane * 8) = o;
}

// ---------------------------------------------------------------------------
// MFMA GEMM v7: R6 staging protocol (depth-2 DMA, 3x48KB bufs, counted vmcnt)
// with the m201-style BARRIER-PAIR PHASE INTERLEAVE inside each stage.
// R6 evidence: pipes SUM (5060cy/stage vs MFMA 1862 + LDS 1917 + HBM) because
// all 8 waves burst their 16 ds_reads together — every wave's operands land
// at the END of the ~1540cy LDS burst, then the MFMA bulk runs with LDS idle.
// Fix: 4 phases/stage, each {reads(2-6) ∥ DMA-chunk -> s_barrier ->
// lgkmcnt(0) -> setprio(1) -> MFMA cluster -> setprio(0) -> s_barrier}.
// Small per-phase LDS bursts overlap with other waves' MFMAs; close barrier
// bounds drift to 1 phase. R5's failure lacked the barrier pairs (waves
// stayed read-burst-aligned); this is the faithful template.
//   P1: fah0-3,bh0-1 +DMA-A    -> 8 MFMA  acch[:][0..1]
//   P2: bh2-3,bl0-1  +DMA-Bh   -> 8 MFMA  acch[:][2..3]
//   P3: bl2-3,fal0-1 +DMA-Bl   -> 8 MFMA  accl += fah*bl[0..1]
//   P4: fal2-3                 -> 24 MFMA accl += fah*bl[2..3], fal*bh[:]
// Inter-stage wait folds into P4's close: vmcnt(6) (DMA(s+1) stays in
// flight), vmcnt(0) at the tail. Rule-18 sched_barrier(0) after every wait.
// Buffer-reuse safety: all reads of buf(s-1) drained (per-phase lgkmcnt(0))
// before P4close(s-1)'s barrier, which precedes any stage-s DMA issue.
template <bool HAS_A2, bool RELU, int K>
__global__ __launch_bounds__(512, 2) void mfma_gemm(
    const f16* __restrict__ A1, const f16* __restrict__ A2,
    const f16* __restrict__ B1h, const f16* __restrict__ B1l,
    const f16* __restrict__ B2h, const f16* __restrict__ B2l,
    const float* __restrict__ bias, f16* __restrict__ C) {
    // per-stage buffer (halves): [A-hi 128x32][A-lo][B-hi 256x32][B-lo]
    constexpr int OAH = 0, OAL = 4096, OBH = 8192, OBL = 16384, BUFH = 24576;
    __shared__ __align__(16) f16 lds[3 * BUFH];   // 144 KB

    const int t = threadIdx.x;
    const int m0 = blockIdx.x * 128;
    const int lane = t & 63;
    const int wid = t >> 6;        // 0..7
    const int wr = wid >> 2;       // 0..1 : row  half (64 rows)
    const int wc = wid & 3;        // 0..3 : col quarter (64 cols)
    const int quad = lane >> 4;
    const int l16 = lane & 15;

    // staging geometry: wave w stages rows [w*16, w*16+16), lane -> (row, q)
    const int ra_ = wid * 16 + (lane >> 2);
    const int qs_ = (lane & 3) ^ ((ra_ >> 1) & 3);   // inverse-swizzled quad
    const int ko_ = qs_ * 8;

    f32x4 acch[4][4], accl[4][4];   // [mt][nt]
#pragma unroll
    for (int a = 0; a < 4; a++)
#pragma unroll
        for (int b = 0; b < 4; b++) {
            acch[a][b] = (f32x4){0.f, 0.f, 0.f, 0.f};
            accl[a][b] = (f32x4){0.f, 0.f, 0.f, 0.f};
        }

    constexpr int NMAT = HAS_A2 ? 2 : 1;
    constexpr int NST = (K / 32) * NMAT;

#define CHUNK_A(S, BUF)                                                        \
    {                                                                          \
        const int mat_ = HAS_A2 ? ((S) & 1) : 0;                               \
        const int kb_ = (HAS_A2 ? ((S) >> 1) : (S)) * 32;                      \
        const f16* A_ = (mat_ == 0) ? A1 : A2;                                 \
        f16* const dst_ = lds + (BUF) * BUFH + wid * 512;                      \
        const size_t arow_ = (size_t)(m0 + ra_) * (2 * K) + kb_ + ko_;         \
        dma16(A_ + arow_, dst_ + OAH);                                         \
        dma16(A_ + arow_ + K, dst_ + OAL);                                     \
    }
#define CHUNK_BH(S, BUF)                                                       \
    {                                                                          \
        const int mat_ = HAS_A2 ? ((S) & 1) : 0;                               \
        const int kb_ = (HAS_A2 ? ((S) >> 1) : (S)) * 32;                      \
        const f16* Bh_ = (mat_ == 0) ? B1h : B2h;                              \
        f16* const dst_ = lds + (BUF) * BUFH + wid * 512;                      \
        const size_t brow_ = (size_t)ra_ * K + kb_ + ko_;                      \
        dma16(Bh_ + brow_, dst_ + OBH);                                        \
        dma16(Bh_ + brow_ + (size_t)128 * K, dst_ + OBH + 4096);               \
    }
#define CHUNK_BL(S, BUF)                                                       \
    {                                                                          \
        const int mat_ = HAS_A2 ? ((S) & 1) : 0;                               \
        const int kb_ = (HAS_A2 ? ((S) >> 1) : (S)) * 32;                      \
        const f16* Bl_ = (mat_ == 0) ? B1l : B2l;                              \
        f16* const dst_ = lds + (BUF) * BUFH + wid * 512;                      \
        const size_t brow_ = (size_t)ra_ * K + kb_ + ko_;                      \
        dma16(Bl_ + brow_, dst_ + OBL);                                        \
        dma16(Bl_ + brow_ + (size_t)128 * K, dst_ + OBL + 4096);               \
    }

#define PHASE_OPEN()                                                           \
    __builtin_amdgcn_s_barrier();                                              \
    asm volatile("s_waitcnt lgkmcnt(0)" ::: "memory");                         \
    __builtin_amdgcn_sched_barrier(0);                                         \
    __builtin_amdgcn_s_setprio(1)
#define PHASE_CLOSE()                                                          \
    __builtin_amdgcn_s_setprio(0);                                             \
    __builtin_amdgcn_sched_barrier(0);                                         \
    __builtin_amdgcn_s_barrier()

#define MFMA(D, X, Y) D = __builtin_amdgcn_mfma_f32_16x16x32_f16(X, Y, D, 0, 0, 0)

    // ---- prologue: depth-2 prefetch into bufs 0 and 1 ----
    CHUNK_A(0, 0); CHUNK_BH(0, 0); CHUNK_BL(0, 0);
    asm volatile("" ::: "memory");
    if (NST > 1) { CHUNK_A(1, 1); CHUNK_BH(1, 1); CHUNK_BL(1, 1); }
    if (NST > 1) { asm volatile("s_waitcnt vmcnt(6)" ::: "memory"); }
    else         { asm volatile("s_waitcnt vmcnt(0)" ::: "memory"); }
    __builtin_amdgcn_s_barrier();
    __builtin_amdgcn_sched_barrier(0);

    int buf = 0;   // s % 3
    for (int s = 0; s < NST; s++) {
        const bool pf = (s + 2 < NST);
        int nb = buf + 2; if (nb >= 3) nb -= 3;
        const f16* cb = lds + buf * BUFH;
        const f16* sAh = cb + OAH;
        const f16* sAl = cb + OAL;
        const f16* sBh = cb + OBH;
        const f16* sBl = cb + OBL;
        f16x8 fah[4], fal[4], bh[4], bl[4];
        const int ar0 = swz(wr * 64 + 0 * 16 + l16, quad);
        const int ar1 = swz(wr * 64 + 1 * 16 + l16, quad);
        const int ar2 = swz(wr * 64 + 2 * 16 + l16, quad);
        const int ar3 = swz(wr * 64 + 3 * 16 + l16, quad);
        const int br0 = swz(wc * 64 + 0 * 16 + l16, quad);
        const int br1 = swz(wc * 64 + 1 * 16 + l16, quad);
        const int br2 = swz(wc * 64 + 2 * 16 + l16, quad);
        const int br3 = swz(wc * 64 + 3 * 16 + l16, quad);

        // ---------------- P1: fah0-3, bh0-1 | DMA-A | acch[:][0..1] --------
        fah[0] = *(const f16x8*)(sAh + ar0);
        fah[1] = *(const f16x8*)(sAh + ar1);
        fah[2] = *(const f16x8*)(sAh + ar2);
        fah[3] = *(const f16x8*)(sAh + ar3);
        bh[0]  = *(const f16x8*)(sBh + br0);
        bh[1]  = *(const f16x8*)(sBh + br1);
        if (pf) CHUNK_A(s + 2, nb);
        PHASE_OPEN();
#pragma unroll
        for (int mt = 0; mt < 4; mt++) MFMA(acch[mt][0], fah[mt], bh[0]);
#pragma unroll
        for (int mt = 0; mt < 4; mt++) MFMA(acch[mt][1], fah[mt], bh[1]);
        PHASE_CLOSE();

        // ---------------- P2: bh2-3, bl0-1 | DMA-Bh | acch[:][2..3] --------
        bh[2] = *(const f16x8*)(sBh + br2);
        bh[3] = *(const f16x8*)(sBh + br3);
        bl[0] = *(const f16x8*)(sBl + br0);
        bl[1] = *(const f16x8*)(sBl + br1);
        if (pf) CHUNK_BH(s + 2, nb);
        PHASE_OPEN();
#pragma unroll
        for (int mt = 0; mt < 4; mt++) MFMA(acch[mt][2], fah[mt], bh[2]);
#pragma unroll
        for (int mt = 0; mt < 4; mt++) MFMA(acch[mt][3], fah[mt], bh[3]);
        PHASE_CLOSE();

        // ---------------- P3: bl2-3, fal0-1 | DMA-Bl | accl += fah*bl01 ----
        bl[2]  = *(const f16x8*)(sBl + br2);
        bl[3]  = *(const f16x8*)(sBl + br3);
        fal[0] = *(const f16x8*)(sAl + ar0);
        fal[1] = *(const f16x8*)(sAl + ar1);
        if (pf) CHUNK_BL(s + 2, nb);
        PHASE_OPEN();
#pragma unroll
        for (int mt = 0; mt < 4; mt++) MFMA(accl[mt][0], fah[mt], bl[0]);
#pragma unroll
        for (int mt = 0; mt < 4; mt++) MFMA(accl[mt][1], fah[mt], bl[1]);
        PHASE_CLOSE();

        // ---------------- P4: fal2-3 | accl += fah*bl23 + fal*bh -----------
        fal[2] = *(const f16x8*)(sAl + ar2);
        fal[3] = *(const f16x8*)(sAl + ar3);
        PHASE_OPEN();
#pragma unroll
        for (int mt = 0; mt < 4; mt++) MFMA(accl[mt][2], fah[mt], bl[2]);
#pragma unroll
        for (int mt = 0; mt < 4; mt++) MFMA(accl[mt][3], fah[mt], bl[3]);
#pragma unroll
        for (int nt = 0; nt < 4; nt++)
#pragma unroll
            for (int mt = 0; mt < 4; mt++) MFMA(accl[mt][nt], fal[mt], bh[nt]);
        __builtin_amdgcn_s_setprio(0);
        __builtin_amdgcn_sched_barrier(0);
        // inter-stage wait: require DMA(s+1) retired; DMA(s+2) may fly.
        if (s < NST - 2) { asm volatile("s_waitcnt vmcnt(6)" ::: "memory"); }
        else             { asm volatile("s_waitcnt vmcnt(0)" ::: "memory"); }
        __builtin_amdgcn_s_barrier();
        __builtin_amdgcn_sched_barrier(0);

        buf = (buf == 2) ? 0 : buf + 1;
    }
#undef CHUNK_A
#undef CHUNK_BH
#undef CHUNK_BL
#undef PHASE_OPEN
#undef PHASE_CLOSE
#undef MFMA

#pragma unroll
    for (int mt = 0; mt < 4; mt++) {
#pragma unroll
        for (int nt = 0; nt < 4; nt++) {
            const int col = wc * 64 + nt * 16 + l16;
            const float bv = bias[col];
#pragma unroll
            for (int r = 0; r < 4; r++) {
                const int row = m0 + wr * 64 + mt * 16 + quad * 4 + r;
                float v = acch[mt][nt][r] + accl[mt][nt][r] * INV_LO + bv;
                if (RELU) v = fmaxf(v, 0.f);
                f16 hi, lo;
                split2(v, hi, lo);
                C[(size_t)row * HSTR + col] = hi;
                C[(size_t)row * HSTR + HIDDIM + col] = lo;
            }
        }
    }
}

// ---------------------------------------------------------------------------
// Segment-mean of interleaved final h -> G[6000][256] fp32.
__global__ void readout_mean_kernel(const f16* __restrict__ H,
                                    const int* __restrict__ scopes, float* __restrict__ G) {
    int g = blockIdx.x;
    int n = threadIdx.x;
    int start = scopes[g * 2 + 0];
    int len = scopes[g * 2 + 1];
    float s = 0.f;
    for (int j = 0; j < len; j++) {
        const f16* row = H + (size_t)(start + j) * HSTR;
        s += (float)row[n] + (float)row[HIDDIM + n] * INV_LO;
    }
    int d = len > 1 ? len : 1;
    G[(size_t)g * HIDDIM + n] = s / (float)d;
}

// ---------------------------------------------------------------------------
// Tiny fp32 GEMM: out[g][n] = G[g][:] . W_out[n][:] + b_out[n], g<6000.
__global__ __launch_bounds__(256) void out_gemm_kernel(
    const float* __restrict__ G, const float* __restrict__ W,
    const float* __restrict__ bias, float* __restrict__ out) {
    __shared__ float sG[16 * 256];
    const int g0 = blockIdx.x * 16;
    const int t = threadIdx.x;
#pragma unroll
    for (int i = 0; i < 16; i++) sG[i * 256 + t] = G[(size_t)(g0 + i) * 256 + t];
    __syncthreads();
    const float bv = bias[t];
    const float* wrow = W + (size_t)t * 256;   // W[n][k] row-major
    float acc[16];
#pragma unroll
    for (int g = 0; g < 16; g++) acc[g] = 0.f;
    for (int k = 0; k < 256; k += 4) {
        const float4 w = *(const float4*)(wrow + k);
#pragma unroll
        for (int g = 0; g < 16; g++) {
            const float4 a = *(const float4*)(sG + g * 256 + k);   // broadcast
            acc[g] = fmaf(a.x, w.x, acc[g]);
            acc[g] = fmaf(a.y, w.y, acc[g]);
            acc[g] = fmaf(a.z, w.z, acc[g]);
            acc[g] = fmaf(a.w, w.w, acc[g]);
        }
    }
#pragma unroll
    for (int g = 0; g < 16; g++) out[(size_t)(g0 + g) * 256 + t] = acc[g] + bv;
}

// ---------------------------------------------------------------------------
extern "C" void kernel_launch(void* const* d_in, const int* in_sizes, int n_in,
                              void* d_out, int out_size, void* d_ws, size_t ws_size,
                              hipStream_t stream) {
    const int* a_features = (const int*)d_in[0];
    const int* b_features = (const int*)d_in[1];
    const int* a_scopes   = (const int*)d_in[2];
    const float* emb      = (const float*)d_in[3];
    const float* W_in     = (const float*)d_in[4];
    const float* b_in     = (const float*)d_in[5];
    const float* W_self   = (const float*)d_in[6];
    const float* b_self   = (const float*)d_in[7];
    const float* W_neigh  = (const float*)d_in[8];
    const float* b_neigh  = (const float*)d_in[9];
    const float* W_out    = (const float*)d_in[10];
    const float* b_out    = (const float*)d_in[11];

    if (g_pool == nullptr) {
        fill_kernel<<<(out_size + 255) / 256, 256, 0, stream>>>(
            (float*)d_out, 77777.0f, out_size);
        return;
    }

    // ---- pool layout (halves); interleaved h buffers [hi256|lo256] ----
    f16* p = (f16*)g_pool;
    const size_t HB2 = (size_t)MP * HSTR;        // 153,616,384 halves / buffer
    f16* bufA = p;
    f16* bufB = p + HB2;
    f16* bufC = p + 2 * HB2;
    f16* xbuf = p + 3 * HB2;                     // [MP][64] interleaved
    f16* Winh = xbuf + (size_t)MP * XSTR;
    f16* Winl = Winh + HIDDIM * DCOL;
    f16* Wsh  = Winl + HIDDIM * DCOL;
    f16* Wsl  = Wsh + HIDDIM * HIDDIM;
    f16* Wnh  = Wsl + HIDDIM * HIDDIM;
    f16* Wnl  = Wnh + HIDDIM * HIDDIM;
    float* Gmean = (float*)(Wnl + HIDDIM * HIDDIM);        // [6000][256] fp32
    float* bsum  = Gmean + (size_t)NGRAPHS * HIDDIM;
    int* csr = (int*)(bsum + HIDDIM);            // [MP][ECAP]
    int* cnt = csr + (size_t)MP * ECAP;          // [MP]

    constexpr int NPAD = MP - NATOMS;            // 32 pad rows

    // ---- setup (identical every launch) ----
    hipMemsetAsync(cnt, 0, (size_t)MP * sizeof(int), stream);
    csr_build_kernel<<<(2 * NBONDS + 255) / 256, 256, 0, stream>>>(b_features, cnt, csr);
    wsplit_kernel<<<(HIDDIM * DCOL + 255) / 256, 256, 0, stream>>>(W_in, Winh, Winl, HIDDIM * DCOL);
    wsplit_kernel<<<(HIDDIM * HIDDIM + 255) / 256, 256, 0, stream>>>(W_self, Wsh, Wsl, HIDDIM * HIDDIM);
    wsplit_kernel<<<(HIDDIM * HIDDIM + 255) / 256, 256, 0, stream>>>(W_neigh, Wnh, Wnl, HIDDIM * HIDDIM);
    bsum_kernel<<<1, HIDDIM, 0, stream>>>(b_self, b_neigh, bsum);

    // Zero padding rows (pool is persistent; keeps pad lanes deterministic).
    constexpr int PADH = NPAD * HSTR / 2;        // halves -> floats
    fill_kernel<<<(PADH + 255) / 256, 256, 0, stream>>>((float*)(bufA + (size_t)NATOMS * HSTR), 0.f, PADH);
    fill_kernel<<<(PADH + 255) / 256, 256, 0, stream>>>((float*)(bufB + (size_t)NATOMS * HSTR), 0.f, PADH);
    fill_kernel<<<(PADH + 255) / 256, 256, 0, stream>>>((float*)(bufC + (size_t)NATOMS * HSTR), 0.f, PADH);
    constexpr int PADX = NPAD * XSTR / 2;
    fill_kernel<<<(PADX + 255) / 256, 256, 0, stream>>>((float*)(xbuf + (size_t)NATOMS * XSTR), 0.f, PADX);

    // ---- embedding + input linear -> h (bufA) ----
    embed_kernel<<<(NATOMS * DCOL + 255) / 256, 256, 0, stream>>>(a_features, emb, xbuf);
    mfma_gemm<false, false, DCOL><<<MTILES128, 512, 0, stream>>>(
        xbuf, nullptr, Winh, Winl, nullptr, nullptr, b_in, bufA);

    // ---- 3 message-passing steps with rotating buffers ----
    f16* h  = bufA;
    f16* g  = bufB;
    f16* hn = bufC;
    for (int s = 0; s < NSTEPS; s++) {
        agg_kernel<<<NATOMS / 4, 256, 0, stream>>>(h, g, cnt, csr);
        mfma_gemm<true, true, HIDDIM><<<MTILES128, 512, 0, stream>>>(
            h, g, Wsh, Wsl, Wnh, Wnl, bsum, hn);
        f16* old = h;
        h = hn; hn = g; g = old;
    }

    // ---- mean first (linearity), then tiny output linear ----
    readout_mean_kernel<<<NGRAPHS, 256, 0, stream>>>(h, a_scopes, Gmean);
    out_gemm_kernel<<<NGRAPHS / 16, 256, 0, stream>>>(Gmean, W_out, b_out, (float*)d_out);
}

// Round 8
// 1842.596 us; speedup vs baseline: 1.0105x; 1.0105x over previous
//
#include <hip/hip_runtime.h>

#define NATOMS 300000
#define NCOLS 8
#define VOCABSZ 4096
#define DCOL 32
#define HIDDIM 256
#define NBONDS 320000
#define NGRAPHS 6000
#define NSTEPS 3

constexpr int MP = 300032;             // atoms padded to multiple of 256
constexpr int MTILES256 = MP / 256;    // 1172 gemm blocks
constexpr int HSTR = 2 * HIDDIM;       // interleaved h row: [hi256|lo256]
constexpr int XSTR = 2 * DCOL;         // interleaved x row: [hi32|lo32]
constexpr int ECAP = 32;               // CSR slots/atom; P(deg>32) < 1e-20

typedef _Float16 f16;
typedef _Float16 f16x8 __attribute__((ext_vector_type(8)));
typedef float f32x16 __attribute__((ext_vector_type(16)));

// LO_SCALE=64 (was 2048): lo = (x-hi)*64. Chosen so the GEMM's single-acc
// operand scaling (ah/64, bh/64) keeps every fp16 operand normal-range.
constexpr float LO_SCALE = 64.0f;
constexpr float INV_LO   = 1.0f / 64.0f;

__device__ __forceinline__ void split2(float x, f16& h, f16& l) {
    h = (f16)x;
    l = (f16)((x - (float)h) * LO_SCALE);
}

// Async global->LDS DMA, 16B per lane per wave-instruction.
__device__ __forceinline__ void dma16(const f16* g, f16* l) {
    __builtin_amdgcn_global_load_lds(
        (const __attribute__((address_space(1))) uint32_t*)g,
        (__attribute__((address_space(3))) uint32_t*)l, 16, 0, 0);
}

// ---------------------------------------------------------------------------
static void* g_pool = nullptr;
__attribute__((constructor)) static void alloc_pool() {
    void* p = nullptr;
    if (hipMalloc(&p, (size_t)1024 * 1024 * 1024) == hipSuccess) {
        hipMemset(p, 0, (size_t)1024 * 1024 * 1024);
        g_pool = p;
    }
}

// ---------------------------------------------------------------------------
__global__ void fill_kernel(float* out, float v, int n) {
    int i = blockIdx.x * blockDim.x + threadIdx.x;
    if (i < n) out[i] = v;
}

// ---------------------------------------------------------------------------
// Bucketed-CSR build (R6, proven).
__global__ void csr_build_kernel(const int* __restrict__ bf, int* __restrict__ cnt,
                                 int* __restrict__ csr) {
    int e = blockIdx.x * blockDim.x + threadIdx.x;
    if (e >= 2 * NBONDS) return;
    int src, dst;
    if (e < NBONDS) { src = bf[e * 3 + 0]; dst = bf[e * 3 + 1]; }
    else { int i = e - NBONDS; src = bf[i * 3 + 1]; dst = bf[i * 3 + 0]; }
    int slot = atomicAdd(&cnt[dst], 1);
    if (slot < ECAP) csr[dst * ECAP + slot] = src;
}

// ---------------------------------------------------------------------------
__global__ void wsplit_kernel(const float* __restrict__ W, f16* __restrict__ Wh,
                              f16* __restrict__ Wl, int n) {
    int i = blockIdx.x * blockDim.x + threadIdx.x;
    if (i >= n) return;
    split2(W[i], Wh[i], Wl[i]);
}

__global__ void bsum_kernel(const float* __restrict__ a, const float* __restrict__ b,
                            float* __restrict__ o) {
    int i = threadIdx.x;
    o[i] = a[i] + b[i];
}

// ---------------------------------------------------------------------------
// Embedding -> interleaved x rows [hi32|lo32].
__global__ void embed_kernel(const int* __restrict__ af, const float* __restrict__ emb,
                             f16* __restrict__ x) {
    int gid = blockIdx.x * blockDim.x + threadIdx.x;
    int i = gid >> 5, k = gid & 31;
    if (i >= NATOMS) return;
    float s = 0.0f;
#pragma unroll
    for (int c = 0; c < NCOLS; c++) {
        int v = af[i * NCOLS + c];
        int idx = v & (VOCABSZ - 1);
        if (v >= 999999999) idx = 0;
        s += emb[((size_t)c * VOCABSZ + idx) * DCOL + k];
    }
    f16 hi, lo;
    split2(s, hi, lo);
    x[(size_t)i * XSTR + k] = hi;
    x[(size_t)i * XSTR + DCOL + k] = lo;
}

// ---------------------------------------------------------------------------
// Aggregation over bucketed CSR (R6, proven: no nxt-chase, MLP 2-4).
__global__ void agg_kernel(const f16* __restrict__ H, f16* __restrict__ G,
                           const int* __restrict__ cnt, const int* __restrict__ csr) {
    int wid = (blockIdx.x * blockDim.x + threadIdx.x) >> 6;
    int lane = threadIdx.x & 63;
    if (wid >= NATOMS) return;
    float a0 = 0.f, a1 = 0.f, a2 = 0.f, a3 = 0.f,
          a4 = 0.f, a5 = 0.f, a6 = 0.f, a7 = 0.f;
    const int degr = cnt[wid];
    const int deg = degr < ECAP ? degr : ECAP;
    const int* eb = csr + (size_t)wid * ECAP;
    int j = 0;
    for (; j + 2 <= deg; j += 2) {
        const int2 ss = *(const int2*)(eb + j);          // 8B-aligned (j even)
        const f16x8 v0 = *(const f16x8*)(H + (size_t)ss.x * HSTR + lane * 8);
        const f16x8 v1 = *(const f16x8*)(H + (size_t)ss.y * HSTR + lane * 8);
        a0 += (float)v0[0] + (float)v1[0];
        a1 += (float)v0[1] + (float)v1[1];
        a2 += (float)v0[2] + (float)v1[2];
        a3 += (float)v0[3] + (float)v1[3];
        a4 += (float)v0[4] + (float)v1[4];
        a5 += (float)v0[5] + (float)v1[5];
        a6 += (float)v0[6] + (float)v1[6];
        a7 += (float)v0[7] + (float)v1[7];
    }
    if (j < deg) {
        const int s0 = eb[j];
        const f16x8 v = *(const f16x8*)(H + (size_t)s0 * HSTR + lane * 8);
        a0 += (float)v[0]; a1 += (float)v[1]; a2 += (float)v[2]; a3 += (float)v[3];
        a4 += (float)v[4]; a5 += (float)v[5]; a6 += (float)v[6]; a7 += (float)v[7];
    }
    const bool isLo = lane >= 32;
    if (isLo) {
        a0 *= INV_LO; a1 *= INV_LO; a2 *= INV_LO; a3 *= INV_LO;
        a4 *= INV_LO; a5 *= INV_LO; a6 *= INV_LO; a7 *= INV_LO;
    }
    float s0 = a0 + __shfl_xor(a0, 32, 64);
    float s1 = a1 + __shfl_xor(a1, 32, 64);
    float s2 = a2 + __shfl_xor(a2, 32, 64);
    float s3 = a3 + __shfl_xor(a3, 32, 64);
    float s4 = a4 + __shfl_xor(a4, 32, 64);
    float s5 = a5 + __shfl_xor(a5, 32, 64);
    float s6 = a6 + __shfl_xor(a6, 32, 64);
    float s7 = a7 + __shfl_xor(a7, 32, 64);
    f16x8 o;
#define EMIT(J, S)                                                    \
    {                                                                 \
        const f16 hv = (f16)(S);                                      \
        o[J] = isLo ? (f16)(((S) - (float)hv) * LO_SCALE) : hv;       \
    }
    EMIT(0, s0) EMIT(1, s1) EMIT(2, s2) EMIT(3, s3)
    EMIT(4, s4) EMIT(5, s5) EMIT(6, s6) EMIT(7, s7)
#undef EMIT
    *(f16x8*)(G + (size_t)wid * HSTR + lane * 8) = o;
}

// ---------------------------------------------------------------------------
// MFMA GEMM v8: fix the LDS:MFMA ratio (R7 conclusion: 0.81 was unhideable).
// Block 256x256, 8 waves (4m x 2n), wave tile 64x128, 32x32x16 MFMA ->
// 64 FLOP per LDS byte (vs 48), LDS-read 2259cy vs MFMA 3724cy per stage-CU.
// SINGLE fp32 acc (128 VGPR): out = ah*bh + (ah*2^-6)*wl + xl*(bh*2^-6),
// with LO_SCALE=64 at rest so all operands stay fp16-normal; corrections
// absorb into the fp32 acc (added rounding ~2.5e-5, << 9.8e-4 budget).
// Buffers (144KB exactly, as all prior rounds): AH x3 (depth-2 prefetch),
// AL/BH/BL x2 (depth-1; AL HBM-sourced has 2-stage issue lead vs 1600cy
// service; B is L2-resident). One barrier/stage, counted vmcnt(2): AH(s+2)
// is ALWAYS the newest 2 dma in flight (issue order enforced). Monolithic
// compute (R5/R7: intra-stage phases regress). Chunk swizzle c^(row&3):
// derived uniform (8 accesses per 16B-unit class) = conflict-free; staged
// via inverse-swizzled global source, linear LDS dest (rule #21).
template <bool HAS_A2, bool RELU, int K>
__global__ __launch_bounds__(512, 2) void mfma_gemm(
    const f16* __restrict__ A1, const f16* __restrict__ A2,
    const f16* __restrict__ B1h, const f16* __restrict__ B1l,
    const f16* __restrict__ B2h, const f16* __restrict__ B2l,
    const float* __restrict__ bias, f16* __restrict__ C) {
    constexpr int HB = 8192;   // halves per 16KB sub-buffer ([256 rows][32 k])
    __shared__ __align__(16) f16 lds[9 * HB];   // AHx3 | ALx2 | BHx2 | BLx2

    const int t = threadIdx.x;
    const int m0 = blockIdx.x * 256;
    const int lane = t & 63;
    const int wid = t >> 6;        // 0..7
    const int wr = wid >> 1;       // 0..3 : 64-row band
    const int wc = wid & 1;        // 0..1 : 128-col band
    const int l31 = lane & 31;
    const int kg = lane >> 5;      // 0..1 : k-group within 16-k slice

    // staging geometry: lane -> (row 0..127, inverse-swizzled 8-half chunk)
    const int srow = wid * 16 + (lane >> 2);
    const int sko = ((lane & 3) ^ (srow & 3)) * 8;

    f32x16 acc[2][4];
#pragma unroll
    for (int a = 0; a < 2; a++)
#pragma unroll
        for (int b = 0; b < 4; b++)
#pragma unroll
            for (int i = 0; i < 16; i++) acc[a][b][i] = 0.f;

    constexpr int NMAT = HAS_A2 ? 2 : 1;
    constexpr int NST = (K / 32) * NMAT;

#define SRC_DECL(S)                                                            \
    const int mat_ = HAS_A2 ? ((S) & 1) : 0;                                   \
    const int kb_ = (HAS_A2 ? ((S) >> 1) : (S)) * 32;

#define ISSUE_AH(S)                                                            \
    {                                                                          \
        SRC_DECL(S)                                                            \
        const f16* A_ = (mat_ == 0) ? A1 : A2;                                 \
        f16* dst_ = lds + ((S) % 3) * HB + wid * 512;                          \
        dma16(A_ + (size_t)(m0 + srow) * (2 * K) + kb_ + sko, dst_);           \
        dma16(A_ + (size_t)(m0 + srow + 128) * (2 * K) + kb_ + sko, dst_ + 4096); \
    }
#define ISSUE_AL(S)                                                            \
    {                                                                          \
        SRC_DECL(S)                                                            \
        const f16* A_ = (mat_ == 0) ? A1 : A2;                                 \
        f16* dst_ = lds + (3 + ((S) & 1)) * HB + wid * 512;                    \
        dma16(A_ + (size_t)(m0 + srow) * (2 * K) + K + kb_ + sko, dst_);       \
        dma16(A_ + (size_t)(m0 + srow + 128) * (2 * K) + K + kb_ + sko, dst_ + 4096); \
    }
#define ISSUE_BH(S)                                                            \
    {                                                                          \
        SRC_DECL(S)                                                            \
        const f16* B_ = (mat_ == 0) ? B1h : B2h;                               \
        f16* dst_ = lds + (5 + ((S) & 1)) * HB + wid * 512;                    \
        dma16(B_ + (size_t)srow * K + kb_ + sko, dst_);                        \
        dma16(B_ + (size_t)(srow + 128) * K + kb_ + sko, dst_ + 4096);         \
    }
#define ISSUE_BL(S)                                                            \
    {                                                                          \
        SRC_DECL(S)                                                            \
        const f16* B_ = (mat_ == 0) ? B1l : B2l;                               \
        f16* dst_ = lds + (7 + ((S) & 1)) * HB + wid * 512;                    \
        dma16(B_ + (size_t)srow * K + kb_ + sko, dst_);                        \
        dma16(B_ + (size_t)(srow + 128) * K + kb_ + sko, dst_ + 4096);         \
    }

#define MFMA32(D, X, Y) D = __builtin_amdgcn_mfma_f32_32x32x16_f16(X, Y, D, 0, 0, 0)

    // ---- prologue: stage 0 full + AH(1); AH last so vmcnt(2) spares it ----
    ISSUE_AH(0);
    ISSUE_AL(0);
    ISSUE_BH(0);
    ISSUE_BL(0);
    if (NST > 1) {
        ISSUE_AH(1);
        asm volatile("s_waitcnt vmcnt(2)" ::: "memory");
    } else {
        asm volatile("s_waitcnt vmcnt(0)" ::: "memory");
    }
    __builtin_amdgcn_s_barrier();
    __builtin_amdgcn_sched_barrier(0);

    for (int s = 0; s < NST; s++) {
        // issue next-stage loads (AL/BH/BL depth-1, AH depth-2, AH LAST)
        if (s + 1 < NST) { ISSUE_AL(s + 1); ISSUE_BH(s + 1); ISSUE_BL(s + 1); }
        if (s + 2 < NST) { ISSUE_AH(s + 2); }

        const f16* pAH = lds + (s % 3) * HB;
        const f16* pAL = lds + (3 + (s & 1)) * HB;
        const f16* pBH = lds + (5 + (s & 1)) * HB;
        const f16* pBL = lds + (7 + (s & 1)) * HB;

#pragma unroll
        for (int ks = 0; ks < 2; ks++) {
            f16x8 ah[2], ahq[2], al[2], bh[4], bhq[4], bl[4];
#pragma unroll
            for (int mt = 0; mt < 2; mt++) {
                const int r = wr * 64 + mt * 32 + l31;
                const int ad = r * 32 + ((((ks << 1) | kg) ^ (r & 3)) << 3);
                ah[mt] = *(const f16x8*)(pAH + ad);
                al[mt] = *(const f16x8*)(pAL + ad);
                ahq[mt] = ah[mt] * (f16)INV_LO;
            }
#pragma unroll
            for (int nt = 0; nt < 4; nt++) {
                const int r = wc * 128 + nt * 32 + l31;
                const int ad = r * 32 + ((((ks << 1) | kg) ^ (r & 3)) << 3);
                bh[nt] = *(const f16x8*)(pBH + ad);
                bl[nt] = *(const f16x8*)(pBL + ad);
                bhq[nt] = bh[nt] * (f16)INV_LO;
            }
            // P1: hi*hi
#pragma unroll
            for (int nt = 0; nt < 4; nt++)
#pragma unroll
                for (int mt = 0; mt < 2; mt++) MFMA32(acc[mt][nt], ah[mt], bh[nt]);
            // P2: (hi/64)*wl  (wl stored = (W-wh)*64)
#pragma unroll
            for (int nt = 0; nt < 4; nt++)
#pragma unroll
                for (int mt = 0; mt < 2; mt++) MFMA32(acc[mt][nt], ahq[mt], bl[nt]);
            // P3: xl*(wh/64)  (xl stored = (x-xh)*64)
#pragma unroll
            for (int nt = 0; nt < 4; nt++)
#pragma unroll
                for (int mt = 0; mt < 2; mt++) MFMA32(acc[mt][nt], al[mt], bhq[nt]);
        }

        if (s + 1 < NST) {
            // drain own LDS reads (buffer-reuse safety), then counted vmcnt:
            // require AL/BH/BL(s+1) + AH(s+1) retired; allow AH(s+2) (2 newest).
            asm volatile("s_waitcnt lgkmcnt(0)" ::: "memory");
            if (s + 2 < NST) { asm volatile("s_waitcnt vmcnt(2)" ::: "memory"); }
            else             { asm volatile("s_waitcnt vmcnt(0)" ::: "memory"); }
            __builtin_amdgcn_s_barrier();
            __builtin_amdgcn_sched_barrier(0);
        }
    }
#undef SRC_DECL
#undef ISSUE_AH
#undef ISSUE_AL
#undef ISSUE_BH
#undef ISSUE_BL
#undef MFMA32

    // epilogue: 32x32 C/D layout: col = lane&31,
    // row = 4*(lane>>5) + (reg&3) + 8*(reg>>2)   [m74/m101 verified]
#pragma unroll
    for (int mt = 0; mt < 2; mt++) {
#pragma unroll
        for (int nt = 0; nt < 4; nt++) {
            const int col = wc * 128 + nt * 32 + l31;
            const float bv = bias[col];
#pragma unroll
            for (int reg = 0; reg < 16; reg++) {
                const int row = m0 + wr * 64 + mt * 32 + 4 * kg + (reg & 3) + 8 * (reg >> 2);
                float v = acc[mt][nt][reg] + bv;
                if (RELU) v = fmaxf(v, 0.f);
                f16 hi, lo;
                split2(v, hi, lo);
                C[(size_t)row * HSTR + col] = hi;
                C[(size_t)row * HSTR + HIDDIM + col] = lo;
            }
        }
    }
}

// ---------------------------------------------------------------------------
// Segment-mean of interleaved final h -> G[6000][256] fp32.
__global__ void readout_mean_kernel(const f16* __restrict__ H,
                                    const int* __restrict__ scopes, float* __restrict__ G) {
    int g = blockIdx.x;
    int n = threadIdx.x;
    int start = scopes[g * 2 + 0];
    int len = scopes[g * 2 + 1];
    float s = 0.f;
    for (int j = 0; j < len; j++) {
        const f16* row = H + (size_t)(start + j) * HSTR;
        s += (float)row[n] + (float)row[HIDDIM + n] * INV_LO;
    }
    int d = len > 1 ? len : 1;
    G[(size_t)g * HIDDIM + n] = s / (float)d;
}

// ---------------------------------------------------------------------------
// Tiny fp32 GEMM: out[g][n] = G[g][:] . W_out[n][:] + b_out[n], g<6000.
__global__ __launch_bounds__(256) void out_gemm_kernel(
    const float* __restrict__ G, const float* __restrict__ W,
    const float* __restrict__ bias, float* __restrict__ out) {
    __shared__ float sG[16 * 256];
    const int g0 = blockIdx.x * 16;
    const int t = threadIdx.x;
#pragma unroll
    for (int i = 0; i < 16; i++) sG[i * 256 + t] = G[(size_t)(g0 + i) * 256 + t];
    __syncthreads();
    const float bv = bias[t];
    const float* wrow = W + (size_t)t * 256;   // W[n][k] row-major
    float acc[16];
#pragma unroll
    for (int g = 0; g < 16; g++) acc[g] = 0.f;
    for (int k = 0; k < 256; k += 4) {
        const float4 w = *(const float4*)(wrow + k);
#pragma unroll
        for (int g = 0; g < 16; g++) {
            const float4 a = *(const float4*)(sG + g * 256 + k);   // broadcast
            acc[g] = fmaf(a.x, w.x, acc[g]);
            acc[g] = fmaf(a.y, w.y, acc[g]);
            acc[g] = fmaf(a.z, w.z, acc[g]);
            acc[g] = fmaf(a.w, w.w, acc[g]);
        }
    }
#pragma unroll
    for (int g = 0; g < 16; g++) out[(size_t)(g0 + g) * 256 + t] = acc[g] + bv;
}

// ---------------------------------------------------------------------------
extern "C" void kernel_launch(void* const* d_in, const int* in_sizes, int n_in,
                              void* d_out, int out_size, void* d_ws, size_t ws_size,
                              hipStream_t stream) {
    const int* a_features = (const int*)d_in[0];
    const int* b_features = (const int*)d_in[1];
    const int* a_scopes   = (const int*)d_in[2];
    const float* emb      = (const float*)d_in[3];
    const float* W_in     = (const float*)d_in[4];
    const float* b_in     = (const float*)d_in[5];
    const float* W_self   = (const float*)d_in[6];
    const float* b_self   = (const float*)d_in[7];
    const float* W_neigh  = (const float*)d_in[8];
    const float* b_neigh  = (const float*)d_in[9];
    const float* W_out    = (const float*)d_in[10];
    const float* b_out    = (const float*)d_in[11];

    if (g_pool == nullptr) {
        fill_kernel<<<(out_size + 255) / 256, 256, 0, stream>>>(
            (float*)d_out, 77777.0f, out_size);
        return;
    }

    // ---- pool layout (halves); interleaved h buffers [hi256|lo256] ----
    f16* p = (f16*)g_pool;
    const size_t HB2 = (size_t)MP * HSTR;        // 153,616,384 halves / buffer
    f16* bufA = p;
    f16* bufB = p + HB2;
    f16* bufC = p + 2 * HB2;
    f16* xbuf = p + 3 * HB2;                     // [MP][64] interleaved
    f16* Winh = xbuf + (size_t)MP * XSTR;
    f16* Winl = Winh + HIDDIM * DCOL;
    f16* Wsh  = Winl + HIDDIM * DCOL;
    f16* Wsl  = Wsh + HIDDIM * HIDDIM;
    f16* Wnh  = Wsl + HIDDIM * HIDDIM;
    f16* Wnl  = Wnh + HIDDIM * HIDDIM;
    float* Gmean = (float*)(Wnl + HIDDIM * HIDDIM);        // [6000][256] fp32
    float* bsum  = Gmean + (size_t)NGRAPHS * HIDDIM;
    int* csr = (int*)(bsum + HIDDIM);            // [MP][ECAP]
    int* cnt = csr + (size_t)MP * ECAP;          // [MP]

    constexpr int NPAD = MP - NATOMS;            // 32 pad rows

    // ---- setup (identical every launch) ----
    hipMemsetAsync(cnt, 0, (size_t)MP * sizeof(int), stream);
    csr_build_kernel<<<(2 * NBONDS + 255) / 256, 256, 0, stream>>>(b_features, cnt, csr);
    wsplit_kernel<<<(HIDDIM * DCOL + 255) / 256, 256, 0, stream>>>(W_in, Winh, Winl, HIDDIM * DCOL);
    wsplit_kernel<<<(HIDDIM * HIDDIM + 255) / 256, 256, 0, stream>>>(W_self, Wsh, Wsl, HIDDIM * HIDDIM);
    wsplit_kernel<<<(HIDDIM * HIDDIM + 255) / 256, 256, 0, stream>>>(W_neigh, Wnh, Wnl, HIDDIM * HIDDIM);
    bsum_kernel<<<1, HIDDIM, 0, stream>>>(b_self, b_neigh, bsum);

    // Zero padding rows (pool is persistent; keeps pad lanes deterministic).
    constexpr int PADH = NPAD * HSTR / 2;        // halves -> floats
    fill_kernel<<<(PADH + 255) / 256, 256, 0, stream>>>((float*)(bufA + (size_t)NATOMS * HSTR), 0.f, PADH);
    fill_kernel<<<(PADH + 255) / 256, 256, 0, stream>>>((float*)(bufB + (size_t)NATOMS * HSTR), 0.f, PADH);
    fill_kernel<<<(PADH + 255) / 256, 256, 0, stream>>>((float*)(bufC + (size_t)NATOMS * HSTR), 0.f, PADH);
    constexpr int PADX = NPAD * XSTR / 2;
    fill_kernel<<<(PADX + 255) / 256, 256, 0, stream>>>((float*)(xbuf + (size_t)NATOMS * XSTR), 0.f, PADX);

    // ---- embedding + input linear -> h (bufA) ----
    embed_kernel<<<(NATOMS * DCOL + 255) / 256, 256, 0, stream>>>(a_features, emb, xbuf);
    mfma_gemm<false, false, DCOL><<<MTILES256, 512, 0, stream>>>(
        xbuf, nullptr, Winh, Winl, nullptr, nullptr, b_in, bufA);

    // ---- 3 message-passing steps with rotating buffers ----
    f16* h  = bufA;
    f16* g  = bufB;
    f16* hn = bufC;
    for (int s = 0; s < NSTEPS; s++) {
        agg_kernel<<<NATOMS / 4, 256, 0, stream>>>(h, g, cnt, csr);
        mfma_gemm<true, true, HIDDIM><<<MTILES256, 512, 0, stream>>>(
            h, g, Wsh, Wsl, Wnh, Wnl, bsum, hn);
        f16* old = h;
        h = hn; hn = g; g = old;
    }

    // ---- mean first (linearity), then tiny output linear ----
    readout_mean_kernel<<<NGRAPHS, 256, 0, stream>>>(h, a_scopes, Gmean);
    out_gemm_kernel<<<NGRAPHS / 16, 256, 0, stream>>>(Gmean, W_out, b_out, (float*)d_out);
}

// Round 9
// 1841.636 us; speedup vs baseline: 1.0110x; 1.0005x over previous
//
#include <hip/hip_runtime.h>

#define NATOMS 300000
#define NCOLS 8
#define VOCABSZ 4096
#define DCOL 32
#define HIDDIM 256
#define NBONDS 320000
#define NGRAPHS 6000
#define NSTEPS 3

constexpr int MP = 300032;             // atoms padded to multiple of 256
constexpr int MTILES256 = MP / 256;    // 1172 gemm blocks
constexpr int HSTR = 2 * HIDDIM;       // interleaved h row: [hi256|lo256]
constexpr int XSTR = 2 * DCOL;         // interleaved x row: [hi32|lo32]
constexpr int ECAP = 32;               // CSR slots/atom; P(deg>32) < 1e-20

typedef _Float16 f16;
typedef _Float16 f16x8 __attribute__((ext_vector_type(8)));
typedef float f32x16 __attribute__((ext_vector_type(16)));

// LO_SCALE=64: lo = (x-hi)*64, so the GEMM's single-acc operand scaling
// (ah/64, bh/64) keeps every fp16 operand normal-range.
constexpr float LO_SCALE = 64.0f;
constexpr float INV_LO   = 1.0f / 64.0f;

__device__ __forceinline__ void split2(float x, f16& h, f16& l) {
    h = (f16)x;
    l = (f16)((x - (float)h) * LO_SCALE);
}

// Async global->LDS DMA, 16B per lane per wave-instruction.
__device__ __forceinline__ void dma16(const f16* g, f16* l) {
    __builtin_amdgcn_global_load_lds(
        (const __attribute__((address_space(1))) uint32_t*)g,
        (__attribute__((address_space(3))) uint32_t*)l, 16, 0, 0);
}

// ---------------------------------------------------------------------------
static void* g_pool = nullptr;
__attribute__((constructor)) static void alloc_pool() {
    void* p = nullptr;
    if (hipMalloc(&p, (size_t)1024 * 1024 * 1024) == hipSuccess) {
        hipMemset(p, 0, (size_t)1024 * 1024 * 1024);
        g_pool = p;
    }
}

// ---------------------------------------------------------------------------
__global__ void fill_kernel(float* out, float v, int n) {
    int i = blockIdx.x * blockDim.x + threadIdx.x;
    if (i < n) out[i] = v;
}

// ---------------------------------------------------------------------------
// Bucketed-CSR build (R6, proven).
__global__ void csr_build_kernel(const int* __restrict__ bf, int* __restrict__ cnt,
                                 int* __restrict__ csr) {
    int e = blockIdx.x * blockDim.x + threadIdx.x;
    if (e >= 2 * NBONDS) return;
    int src, dst;
    if (e < NBONDS) { src = bf[e * 3 + 0]; dst = bf[e * 3 + 1]; }
    else { int i = e - NBONDS; src = bf[i * 3 + 1]; dst = bf[i * 3 + 0]; }
    int slot = atomicAdd(&cnt[dst], 1);
    if (slot < ECAP) csr[dst * ECAP + slot] = src;
}

// ---------------------------------------------------------------------------
__global__ void wsplit_kernel(const float* __restrict__ W, f16* __restrict__ Wh,
                              f16* __restrict__ Wl, int n) {
    int i = blockIdx.x * blockDim.x + threadIdx.x;
    if (i >= n) return;
    split2(W[i], Wh[i], Wl[i]);
}

__global__ void bsum_kernel(const float* __restrict__ a, const float* __restrict__ b,
                            float* __restrict__ o) {
    int i = threadIdx.x;
    o[i] = a[i] + b[i];
}

// ---------------------------------------------------------------------------
// Embedding -> interleaved x rows [hi32|lo32].
__global__ void embed_kernel(const int* __restrict__ af, const float* __restrict__ emb,
                             f16* __restrict__ x) {
    int gid = blockIdx.x * blockDim.x + threadIdx.x;
    int i = gid >> 5, k = gid & 31;
    if (i >= NATOMS) return;
    float s = 0.0f;
#pragma unroll
    for (int c = 0; c < NCOLS; c++) {
        int v = af[i * NCOLS + c];
        int idx = v & (VOCABSZ - 1);
        if (v >= 999999999) idx = 0;
        s += emb[((size_t)c * VOCABSZ + idx) * DCOL + k];
    }
    f16 hi, lo;
    split2(s, hi, lo);
    x[(size_t)i * XSTR + k] = hi;
    x[(size_t)i * XSTR + DCOL + k] = lo;
}

// ---------------------------------------------------------------------------
// Aggregation over bucketed CSR (R6, proven: no nxt-chase, MLP 2-4).
__global__ void agg_kernel(const f16* __restrict__ H, f16* __restrict__ G,
                           const int* __restrict__ cnt, const int* __restrict__ csr) {
    int wid = (blockIdx.x * blockDim.x + threadIdx.x) >> 6;
    int lane = threadIdx.x & 63;
    if (wid >= NATOMS) return;
    float a0 = 0.f, a1 = 0.f, a2 = 0.f, a3 = 0.f,
          a4 = 0.f, a5 = 0.f, a6 = 0.f, a7 = 0.f;
    const int degr = cnt[wid];
    const int deg = degr < ECAP ? degr : ECAP;
    const int* eb = csr + (size_t)wid * ECAP;
    int j = 0;
    for (; j + 2 <= deg; j += 2) {
        const int2 ss = *(const int2*)(eb + j);          // 8B-aligned (j even)
        const f16x8 v0 = *(const f16x8*)(H + (size_t)ss.x * HSTR + lane * 8);
        const f16x8 v1 = *(const f16x8*)(H + (size_t)ss.y * HSTR + lane * 8);
        a0 += (float)v0[0] + (float)v1[0];
        a1 += (float)v0[1] + (float)v1[1];
        a2 += (float)v0[2] + (float)v1[2];
        a3 += (float)v0[3] + (float)v1[3];
        a4 += (float)v0[4] + (float)v1[4];
        a5 += (float)v0[5] + (float)v1[5];
        a6 += (float)v0[6] + (float)v1[6];
        a7 += (float)v0[7] + (float)v1[7];
    }
    if (j < deg) {
        const int s0 = eb[j];
        const f16x8 v = *(const f16x8*)(H + (size_t)s0 * HSTR + lane * 8);
        a0 += (float)v[0]; a1 += (float)v[1]; a2 += (float)v[2]; a3 += (float)v[3];
        a4 += (float)v[4]; a5 += (float)v[5]; a6 += (float)v[6]; a7 += (float)v[7];
    }
    const bool isLo = lane >= 32;
    if (isLo) {
        a0 *= INV_LO; a1 *= INV_LO; a2 *= INV_LO; a3 *= INV_LO;
        a4 *= INV_LO; a5 *= INV_LO; a6 *= INV_LO; a7 *= INV_LO;
    }
    float s0 = a0 + __shfl_xor(a0, 32, 64);
    float s1 = a1 + __shfl_xor(a1, 32, 64);
    float s2 = a2 + __shfl_xor(a2, 32, 64);
    float s3 = a3 + __shfl_xor(a3, 32, 64);
    float s4 = a4 + __shfl_xor(a4, 32, 64);
    float s5 = a5 + __shfl_xor(a5, 32, 64);
    float s6 = a6 + __shfl_xor(a6, 32, 64);
    float s7 = a7 + __shfl_xor(a7, 32, 64);
    f16x8 o;
#define EMIT(J, S)                                                    \
    {                                                                 \
        const f16 hv = (f16)(S);                                      \
        o[J] = isLo ? (f16)(((S) - (float)hv) * LO_SCALE) : hv;       \
    }
    EMIT(0, s0) EMIT(1, s1) EMIT(2, s2) EMIT(3, s3)
    EMIT(4, s4) EMIT(5, s5) EMIT(6, s6) EMIT(7, s7)
#undef EMIT
    *(f16x8*)(G + (size_t)wid * HSTR + lane * 8) = o;
}

// ---------------------------------------------------------------------------
// MFMA GEMM v9 = v8 with the bank-conflict fix. R8 counters: changing the
// chunk swizzle to c^(r&3) cost 4.32e7 SQ_LDS_BANK_CONFLICT (~70us/dispatch):
// for 32 consecutive rows reading 16B each, unit index u=(4r + c^(r&3))%8
// repeats every 4 rows -> 8 lanes per 4-bank group. The VERIFIED form
// c ^ ((r>>1)&3) (r10) covers all 8 units per 8 rows -> conflict-free.
// Restored in BOTH places (staging source sko + fragment read ad).
// Everything else identical to v8: 256x256 block, 8 waves (4m x 2n),
// 32x32x16 MFMA, 64 FLOP/LDS-byte, single fp32 acc
// (out = ah*bh + (ah/64)*wl + xl*(bh/64), LO_SCALE=64), 144KB LDS
// (AHx3 depth-2, AL/BH/BL x2 depth-1), counted vmcnt(2), one barrier/stage,
// monolithic compute (R5/R7: intra-stage phases regress).
template <bool HAS_A2, bool RELU, int K>
__global__ __launch_bounds__(512, 2) void mfma_gemm(
    const f16* __restrict__ A1, const f16* __restrict__ A2,
    const f16* __restrict__ B1h, const f16* __restrict__ B1l,
    const f16* __restrict__ B2h, const f16* __restrict__ B2l,
    const float* __restrict__ bias, f16* __restrict__ C) {
    constexpr int HB = 8192;   // halves per 16KB sub-buffer ([256 rows][32 k])
    __shared__ __align__(16) f16 lds[9 * HB];   // AHx3 | ALx2 | BHx2 | BLx2

    const int t = threadIdx.x;
    const int m0 = blockIdx.x * 256;
    const int lane = t & 63;
    const int wid = t >> 6;        // 0..7
    const int wr = wid >> 1;       // 0..3 : 64-row band
    const int wc = wid & 1;        // 0..1 : 128-col band
    const int l31 = lane & 31;
    const int kg = lane >> 5;      // 0..1 : k-group within 16-k slice

    // staging geometry: lane -> (row 0..127, inverse-swizzled 8-half chunk).
    // VERIFIED swizzle form: chunk ^ ((row>>1)&3). (srow+128)>>1 has the same
    // low 2 bits (128/2=64, 64%4==0) so one sko serves both row-halves.
    const int srow = wid * 16 + (lane >> 2);
    const int sko = ((lane & 3) ^ ((srow >> 1) & 3)) * 8;

    f32x16 acc[2][4];
#pragma unroll
    for (int a = 0; a < 2; a++)
#pragma unroll
        for (int b = 0; b < 4; b++)
#pragma unroll
            for (int i = 0; i < 16; i++) acc[a][b][i] = 0.f;

    constexpr int NMAT = HAS_A2 ? 2 : 1;
    constexpr int NST = (K / 32) * NMAT;

#define SRC_DECL(S)                                                            \
    const int mat_ = HAS_A2 ? ((S) & 1) : 0;                                   \
    const int kb_ = (HAS_A2 ? ((S) >> 1) : (S)) * 32;

#define ISSUE_AH(S)                                                            \
    {                                                                          \
        SRC_DECL(S)                                                            \
        const f16* A_ = (mat_ == 0) ? A1 : A2;                                 \
        f16* dst_ = lds + ((S) % 3) * HB + wid * 512;                          \
        dma16(A_ + (size_t)(m0 + srow) * (2 * K) + kb_ + sko, dst_);           \
        dma16(A_ + (size_t)(m0 + srow + 128) * (2 * K) + kb_ + sko, dst_ + 4096); \
    }
#define ISSUE_AL(S)                                                            \
    {                                                                          \
        SRC_DECL(S)                                                            \
        const f16* A_ = (mat_ == 0) ? A1 : A2;                                 \
        f16* dst_ = lds + (3 + ((S) & 1)) * HB + wid * 512;                    \
        dma16(A_ + (size_t)(m0 + srow) * (2 * K) + K + kb_ + sko, dst_);       \
        dma16(A_ + (size_t)(m0 + srow + 128) * (2 * K) + K + kb_ + sko, dst_ + 4096); \
    }
#define ISSUE_BH(S)                                                            \
    {                                                                          \
        SRC_DECL(S)                                                            \
        const f16* B_ = (mat_ == 0) ? B1h : B2h;                               \
        f16* dst_ = lds + (5 + ((S) & 1)) * HB + wid * 512;                    \
        dma16(B_ + (size_t)srow * K + kb_ + sko, dst_);                        \
        dma16(B_ + (size_t)(srow + 128) * K + kb_ + sko, dst_ + 4096);         \
    }
#define ISSUE_BL(S)                                                            \
    {                                                                          \
        SRC_DECL(S)                                                            \
        const f16* B_ = (mat_ == 0) ? B1l : B2l;                               \
        f16* dst_ = lds + (7 + ((S) & 1)) * HB + wid * 512;                    \
        dma16(B_ + (size_t)srow * K + kb_ + sko, dst_);                        \
        dma16(B_ + (size_t)(srow + 128) * K + kb_ + sko, dst_ + 4096);         \
    }

#define MFMA32(D, X, Y) D = __builtin_amdgcn_mfma_f32_32x32x16_f16(X, Y, D, 0, 0, 0)

    // ---- prologue: stage 0 full + AH(1); AH last so vmcnt(2) spares it ----
    ISSUE_AH(0);
    ISSUE_AL(0);
    ISSUE_BH(0);
    ISSUE_BL(0);
    if (NST > 1) {
        ISSUE_AH(1);
        asm volatile("s_waitcnt vmcnt(2)" ::: "memory");
    } else {
        asm volatile("s_waitcnt vmcnt(0)" ::: "memory");
    }
    __builtin_amdgcn_s_barrier();
    __builtin_amdgcn_sched_barrier(0);

    for (int s = 0; s < NST; s++) {
        // issue next-stage loads (AL/BH/BL depth-1, AH depth-2, AH LAST)
        if (s + 1 < NST) { ISSUE_AL(s + 1); ISSUE_BH(s + 1); ISSUE_BL(s + 1); }
        if (s + 2 < NST) { ISSUE_AH(s + 2); }

        const f16* pAH = lds + (s % 3) * HB;
        const f16* pAL = lds + (3 + (s & 1)) * HB;
        const f16* pBH = lds + (5 + (s & 1)) * HB;
        const f16* pBL = lds + (7 + (s & 1)) * HB;

#pragma unroll
        for (int ks = 0; ks < 2; ks++) {
            f16x8 ah[2], ahq[2], al[2], bh[4], bhq[4], bl[4];
#pragma unroll
            for (int mt = 0; mt < 2; mt++) {
                const int r = wr * 64 + mt * 32 + l31;
                const int ad = r * 32 + ((((ks << 1) | kg) ^ ((r >> 1) & 3)) << 3);
                ah[mt] = *(const f16x8*)(pAH + ad);
                al[mt] = *(const f16x8*)(pAL + ad);
                ahq[mt] = ah[mt] * (f16)INV_LO;
            }
#pragma unroll
            for (int nt = 0; nt < 4; nt++) {
                const int r = wc * 128 + nt * 32 + l31;
                const int ad = r * 32 + ((((ks << 1) | kg) ^ ((r >> 1) & 3)) << 3);
                bh[nt] = *(const f16x8*)(pBH + ad);
                bl[nt] = *(const f16x8*)(pBL + ad);
                bhq[nt] = bh[nt] * (f16)INV_LO;
            }
            // P1: hi*hi
#pragma unroll
            for (int nt = 0; nt < 4; nt++)
#pragma unroll
                for (int mt = 0; mt < 2; mt++) MFMA32(acc[mt][nt], ah[mt], bh[nt]);
            // P2: (hi/64)*wl  (wl stored = (W-wh)*64)
#pragma unroll
            for (int nt = 0; nt < 4; nt++)
#pragma unroll
                for (int mt = 0; mt < 2; mt++) MFMA32(acc[mt][nt], ahq[mt], bl[nt]);
            // P3: xl*(wh/64)  (xl stored = (x-xh)*64)
#pragma unroll
            for (int nt = 0; nt < 4; nt++)
#pragma unroll
                for (int mt = 0; mt < 2; mt++) MFMA32(acc[mt][nt], al[mt], bhq[nt]);
        }

        if (s + 1 < NST) {
            // drain own LDS reads (buffer-reuse safety), then counted vmcnt:
            // require AL/BH/BL(s+1) + AH(s+1) retired; allow AH(s+2) (2 newest).
            asm volatile("s_waitcnt lgkmcnt(0)" ::: "memory");
            if (s + 2 < NST) { asm volatile("s_waitcnt vmcnt(2)" ::: "memory"); }
            else             { asm volatile("s_waitcnt vmcnt(0)" ::: "memory"); }
            __builtin_amdgcn_s_barrier();
            __builtin_amdgcn_sched_barrier(0);
        }
    }
#undef SRC_DECL
#undef ISSUE_AH
#undef ISSUE_AL
#undef ISSUE_BH
#undef ISSUE_BL
#undef MFMA32

    // epilogue: 32x32 C/D layout: col = lane&31,
    // row = 4*(lane>>5) + (reg&3) + 8*(reg>>2)   [m74/m101 verified]
#pragma unroll
    for (int mt = 0; mt < 2; mt++) {
#pragma unroll
        for (int nt = 0; nt < 4; nt++) {
            const int col = wc * 128 + nt * 32 + l31;
            const float bv = bias[col];
#pragma unroll
            for (int reg = 0; reg < 16; reg++) {
                const int row = m0 + wr * 64 + mt * 32 + 4 * kg + (reg & 3) + 8 * (reg >> 2);
                float v = acc[mt][nt][reg] + bv;
                if (RELU) v = fmaxf(v, 0.f);
                f16 hi, lo;
                split2(v, hi, lo);
                C[(size_t)row * HSTR + col] = hi;
                C[(size_t)row * HSTR + HIDDIM + col] = lo;
            }
        }
    }
}

// ---------------------------------------------------------------------------
// Segment-mean of interleaved final h -> G[6000][256] fp32.
__global__ void readout_mean_kernel(const f16* __restrict__ H,
                                    const int* __restrict__ scopes, float* __restrict__ G) {
    int g = blockIdx.x;
    int n = threadIdx.x;
    int start = scopes[g * 2 + 0];
    int len = scopes[g * 2 + 1];
    float s = 0.f;
    for (int j = 0; j < len; j++) {
        const f16* row = H + (size_t)(start + j) * HSTR;
        s += (float)row[n] + (float)row[HIDDIM + n] * INV_LO;
    }
    int d = len > 1 ? len : 1;
    G[(size_t)g * HIDDIM + n] = s / (float)d;
}

// ---------------------------------------------------------------------------
// Tiny fp32 GEMM: out[g][n] = G[g][:] . W_out[n][:] + b_out[n], g<6000.
__global__ __launch_bounds__(256) void out_gemm_kernel(
    const float* __restrict__ G, const float* __restrict__ W,
    const float* __restrict__ bias, float* __restrict__ out) {
    __shared__ float sG[16 * 256];
    const int g0 = blockIdx.x * 16;
    const int t = threadIdx.x;
#pragma unroll
    for (int i = 0; i < 16; i++) sG[i * 256 + t] = G[(size_t)(g0 + i) * 256 + t];
    __syncthreads();
    const float bv = bias[t];
    const float* wrow = W + (size_t)t * 256;   // W[n][k] row-major
    float acc[16];
#pragma unroll
    for (int g = 0; g < 16; g++) acc[g] = 0.f;
    for (int k = 0; k < 256; k += 4) {
        const float4 w = *(const float4*)(wrow + k);
#pragma unroll
        for (int g = 0; g < 16; g++) {
            const float4 a = *(const float4*)(sG + g * 256 + k);   // broadcast
            acc[g] = fmaf(a.x, w.x, acc[g]);
            acc[g] = fmaf(a.y, w.y, acc[g]);
            acc[g] = fmaf(a.z, w.z, acc[g]);
            acc[g] = fmaf(a.w, w.w, acc[g]);
        }
    }
#pragma unroll
    for (int g = 0; g < 16; g++) out[(size_t)(g0 + g) * 256 + t] = acc[g] + bv;
}

// ---------------------------------------------------------------------------
extern "C" void kernel_launch(void* const* d_in, const int* in_sizes, int n_in,
                              void* d_out, int out_size, void* d_ws, size_t ws_size,
                              hipStream_t stream) {
    const int* a_features = (const int*)d_in[0];
    const int* b_features = (const int*)d_in[1];
    const int* a_scopes   = (const int*)d_in[2];
    const float* emb      = (const float*)d_in[3];
    const float* W_in     = (const float*)d_in[4];
    const float* b_in     = (const float*)d_in[5];
    const float* W_self   = (const float*)d_in[6];
    const float* b_self   = (const float*)d_in[7];
    const float* W_neigh  = (const float*)d_in[8];
    const float* b_neigh  = (const float*)d_in[9];
    const float* W_out    = (const float*)d_in[10];
    const float* b_out    = (const float*)d_in[11];

    if (g_pool == nullptr) {
        fill_kernel<<<(out_size + 255) / 256, 256, 0, stream>>>(
            (float*)d_out, 77777.0f, out_size);
        return;
    }

    // ---- pool layout (halves); interleaved h buffers [hi256|lo256] ----
    f16* p = (f16*)g_pool;
    const size_t HB2 = (size_t)MP * HSTR;        // 153,616,384 halves / buffer
    f16* bufA = p;
    f16* bufB = p + HB2;
    f16* bufC = p + 2 * HB2;
    f16* xbuf = p + 3 * HB2;                     // [MP][64] interleaved
    f16* Winh = xbuf + (size_t)MP * XSTR;
    f16* Winl = Winh + HIDDIM * DCOL;
    f16* Wsh  = Winl + HIDDIM * DCOL;
    f16* Wsl  = Wsh + HIDDIM * HIDDIM;
    f16* Wnh  = Wsl + HIDDIM * HIDDIM;
    f16* Wnl  = Wnh + HIDDIM * HIDDIM;
    float* Gmean = (float*)(Wnl + HIDDIM * HIDDIM);        // [6000][256] fp32
    float* bsum  = Gmean + (size_t)NGRAPHS * HIDDIM;
    int* csr = (int*)(bsum + HIDDIM);            // [MP][ECAP]
    int* cnt = csr + (size_t)MP * ECAP;          // [MP]

    constexpr int NPAD = MP - NATOMS;            // 32 pad rows

    // ---- setup (identical every launch) ----
    hipMemsetAsync(cnt, 0, (size_t)MP * sizeof(int), stream);
    csr_build_kernel<<<(2 * NBONDS + 255) / 256, 256, 0, stream>>>(b_features, cnt, csr);
    wsplit_kernel<<<(HIDDIM * DCOL + 255) / 256, 256, 0, stream>>>(W_in, Winh, Winl, HIDDIM * DCOL);
    wsplit_kernel<<<(HIDDIM * HIDDIM + 255) / 256, 256, 0, stream>>>(W_self, Wsh, Wsl, HIDDIM * HIDDIM);
    wsplit_kernel<<<(HIDDIM * HIDDIM + 255) / 256, 256, 0, stream>>>(W_neigh, Wnh, Wnl, HIDDIM * HIDDIM);
    bsum_kernel<<<1, HIDDIM, 0, stream>>>(b_self, b_neigh, bsum);

    // Zero padding rows (pool is persistent; keeps pad lanes deterministic).
    constexpr int PADH = NPAD * HSTR / 2;        // halves -> floats
    fill_kernel<<<(PADH + 255) / 256, 256, 0, stream>>>((float*)(bufA + (size_t)NATOMS * HSTR), 0.f, PADH);
    fill_kernel<<<(PADH + 255) / 256, 256, 0, stream>>>((float*)(bufB + (size_t)NATOMS * HSTR), 0.f, PADH);
    fill_kernel<<<(PADH + 255) / 256, 256, 0, stream>>>((float*)(bufC + (size_t)NATOMS * HSTR), 0.f, PADH);
    constexpr int PADX = NPAD * XSTR / 2;
    fill_kernel<<<(PADX + 255) / 256, 256, 0, stream>>>((float*)(xbuf + (size_t)NATOMS * XSTR), 0.f, PADX);

    // ---- embedding + input linear -> h (bufA) ----
    embed_kernel<<<(NATOMS * DCOL + 255) / 256, 256, 0, stream>>>(a_features, emb, xbuf);
    mfma_gemm<false, false, DCOL><<<MTILES256, 512, 0, stream>>>(
        xbuf, nullptr, Winh, Winl, nullptr, nullptr, b_in, bufA);

    // ---- 3 message-passing steps with rotating buffers ----
    f16* h  = bufA;
    f16* g  = bufB;
    f16* hn = bufC;
    for (int s = 0; s < NSTEPS; s++) {
        agg_kernel<<<NATOMS / 4, 256, 0, stream>>>(h, g, cnt, csr);
        mfma_gemm<true, true, HIDDIM><<<MTILES256, 512, 0, stream>>>(
            h, g, Wsh, Wsl, Wnh, Wnl, bsum, hn);
        f16* old = h;
        h = hn; hn = g; g = old;
    }

    // ---- mean first (linearity), then tiny output linear ----
    readout_mean_kernel<<<NGRAPHS, 256, 0, stream>>>(h, a_scopes, Gmean);
    out_gemm_kernel<<<NGRAPHS / 16, 256, 0, stream>>>(Gmean, W_out, b_out, (float*)d_out);
}

// Round 10
// 1791.324 us; speedup vs baseline: 1.0394x; 1.0281x over previous
//
#include <hip/hip_runtime.h>

#define NATOMS 300000
#define NCOLS 8
#define VOCABSZ 4096
#define DCOL 32
#define HIDDIM 256
#define NBONDS 320000
#define NGRAPHS 6000
#define NSTEPS 3

constexpr int MP = 300032;             // atoms padded to multiple of 256
constexpr int MTILES256 = MP / 256;    // 1172 gemm blocks
constexpr int HSTR = 2 * HIDDIM;       // interleaved h row: [hi256|lo256]
constexpr int XSTR = 2 * DCOL;         // interleaved x row: [hi32|lo32]
constexpr int ECAP = 32;               // CSR slots/atom; P(deg>32) < 1e-20

typedef _Float16 f16;
typedef _Float16 f16x8 __attribute__((ext_vector_type(8)));
typedef float f32x16 __attribute__((ext_vector_type(16)));

// LO_SCALE=64: lo = (x-hi)*64, so the GEMM's single-acc operand scaling
// (ah/64, al/64) keeps every fp16 operand normal-range.
constexpr float LO_SCALE = 64.0f;
constexpr float INV_LO   = 1.0f / 64.0f;

__device__ __forceinline__ void split2(float x, f16& h, f16& l) {
    h = (f16)x;
    l = (f16)((x - (float)h) * LO_SCALE);
}

// Async global->LDS DMA, 16B per lane per wave-instruction.
__device__ __forceinline__ void dma16(const f16* g, f16* l) {
    __builtin_amdgcn_global_load_lds(
        (const __attribute__((address_space(1))) uint32_t*)g,
        (__attribute__((address_space(3))) uint32_t*)l, 16, 0, 0);
}

// ---------------------------------------------------------------------------
static void* g_pool = nullptr;
__attribute__((constructor)) static void alloc_pool() {
    void* p = nullptr;
    if (hipMalloc(&p, (size_t)1024 * 1024 * 1024) == hipSuccess) {
        hipMemset(p, 0, (size_t)1024 * 1024 * 1024);
        g_pool = p;
    }
}

// ---------------------------------------------------------------------------
__global__ void fill_kernel(float* out, float v, int n) {
    int i = blockIdx.x * blockDim.x + threadIdx.x;
    if (i < n) out[i] = v;
}

// ---------------------------------------------------------------------------
// Bucketed-CSR build (R6, proven).
__global__ void csr_build_kernel(const int* __restrict__ bf, int* __restrict__ cnt,
                                 int* __restrict__ csr) {
    int e = blockIdx.x * blockDim.x + threadIdx.x;
    if (e >= 2 * NBONDS) return;
    int src, dst;
    if (e < NBONDS) { src = bf[e * 3 + 0]; dst = bf[e * 3 + 1]; }
    else { int i = e - NBONDS; src = bf[i * 3 + 1]; dst = bf[i * 3 + 0]; }
    int slot = atomicAdd(&cnt[dst], 1);
    if (slot < ECAP) csr[dst * ECAP + slot] = src;
}

// ---------------------------------------------------------------------------
__global__ void wsplit_kernel(const float* __restrict__ W, f16* __restrict__ Wh,
                              f16* __restrict__ Wl, int n) {
    int i = blockIdx.x * blockDim.x + threadIdx.x;
    if (i >= n) return;
    split2(W[i], Wh[i], Wl[i]);
}

__global__ void bsum_kernel(const float* __restrict__ a, const float* __restrict__ b,
                            float* __restrict__ o) {
    int i = threadIdx.x;
    o[i] = a[i] + b[i];
}

// ---------------------------------------------------------------------------
// Embedding -> interleaved x rows [hi32|lo32].
__global__ void embed_kernel(const int* __restrict__ af, const float* __restrict__ emb,
                             f16* __restrict__ x) {
    int gid = blockIdx.x * blockDim.x + threadIdx.x;
    int i = gid >> 5, k = gid & 31;
    if (i >= NATOMS) return;
    float s = 0.0f;
#pragma unroll
    for (int c = 0; c < NCOLS; c++) {
        int v = af[i * NCOLS + c];
        int idx = v & (VOCABSZ - 1);
        if (v >= 999999999) idx = 0;
        s += emb[((size_t)c * VOCABSZ + idx) * DCOL + k];
    }
    f16 hi, lo;
    split2(s, hi, lo);
    x[(size_t)i * XSTR + k] = hi;
    x[(size_t)i * XSTR + DCOL + k] = lo;
}

// ---------------------------------------------------------------------------
// Aggregation over bucketed CSR (R6, proven: no nxt-chase, MLP 2-4).
__global__ void agg_kernel(const f16* __restrict__ H, f16* __restrict__ G,
                           const int* __restrict__ cnt, const int* __restrict__ csr) {
    int wid = (blockIdx.x * blockDim.x + threadIdx.x) >> 6;
    int lane = threadIdx.x & 63;
    if (wid >= NATOMS) return;
    float a0 = 0.f, a1 = 0.f, a2 = 0.f, a3 = 0.f,
          a4 = 0.f, a5 = 0.f, a6 = 0.f, a7 = 0.f;
    const int degr = cnt[wid];
    const int deg = degr < ECAP ? degr : ECAP;
    const int* eb = csr + (size_t)wid * ECAP;
    int j = 0;
    for (; j + 2 <= deg; j += 2) {
        const int2 ss = *(const int2*)(eb + j);          // 8B-aligned (j even)
        const f16x8 v0 = *(const f16x8*)(H + (size_t)ss.x * HSTR + lane * 8);
        const f16x8 v1 = *(const f16x8*)(H + (size_t)ss.y * HSTR + lane * 8);
        a0 += (float)v0[0] + (float)v1[0];
        a1 += (float)v0[1] + (float)v1[1];
        a2 += (float)v0[2] + (float)v1[2];
        a3 += (float)v0[3] + (float)v1[3];
        a4 += (float)v0[4] + (float)v1[4];
        a5 += (float)v0[5] + (float)v1[5];
        a6 += (float)v0[6] + (float)v1[6];
        a7 += (float)v0[7] + (float)v1[7];
    }
    if (j < deg) {
        const int s0 = eb[j];
        const f16x8 v = *(const f16x8*)(H + (size_t)s0 * HSTR + lane * 8);
        a0 += (float)v[0]; a1 += (float)v[1]; a2 += (float)v[2]; a3 += (float)v[3];
        a4 += (float)v[4]; a5 += (float)v[5]; a6 += (float)v[6]; a7 += (float)v[7];
    }
    const bool isLo = lane >= 32;
    if (isLo) {
        a0 *= INV_LO; a1 *= INV_LO; a2 *= INV_LO; a3 *= INV_LO;
        a4 *= INV_LO; a5 *= INV_LO; a6 *= INV_LO; a7 *= INV_LO;
    }
    float s0 = a0 + __shfl_xor(a0, 32, 64);
    float s1 = a1 + __shfl_xor(a1, 32, 64);
    float s2 = a2 + __shfl_xor(a2, 32, 64);
    float s3 = a3 + __shfl_xor(a3, 32, 64);
    float s4 = a4 + __shfl_xor(a4, 32, 64);
    float s5 = a5 + __shfl_xor(a5, 32, 64);
    float s6 = a6 + __shfl_xor(a6, 32, 64);
    float s7 = a7 + __shfl_xor(a7, 32, 64);
    f16x8 o;
#define EMIT(J, S)                                                    \
    {                                                                 \
        const f16 hv = (f16)(S);                                      \
        o[J] = isLo ? (f16)(((S) - (float)hv) * LO_SCALE) : hv;       \
    }
    EMIT(0, s0) EMIT(1, s1) EMIT(2, s2) EMIT(3, s3)
    EMIT(4, s4) EMIT(5, s5) EMIT(6, s6) EMIT(7, s7)
#undef EMIT
    *(f16x8*)(G + (size_t)wid * HSTR + lane * 8) = o;
}

// ---------------------------------------------------------------------------
// MFMA GEMM v10 = v9 fully UNROLLED. R9 counters: VALUBusy 20.6% =
// ~2120cy/stage/SIMD = ~530 VALU insts/wave/stage — the runtime-s loop
// recomputes s%3, s&1, mat_ pointer ternaries, twelve 64-bit DMA addresses
// and 24 (stage-invariant!) read offsets EVERY stage, and that integer
// stream serializes against MFMA on the shared SIMD issue. NST is a
// template constant -> #pragma unroll makes every selection compile-time:
// DMA addrs fold to base+immediate, read offsets CSE once, vmcnt choice
// static. Also: scale only A-side fragments (ahq=ah/64, alq=al/64; P3 =
// alq*bh == xl*(wh/64) identically) — drops 8 pk_muls/ks. Everything else
// (staging, r10 swizzle, AHx3/ALx2/BHx2/BLx2 144KB, counted vmcnt(2),
// one barrier/stage, monolithic compute) byte-identical to v9.
template <bool HAS_A2, bool RELU, int K>
__global__ __launch_bounds__(512, 2) void mfma_gemm(
    const f16* __restrict__ A1, const f16* __restrict__ A2,
    const f16* __restrict__ B1h, const f16* __restrict__ B1l,
    const f16* __restrict__ B2h, const f16* __restrict__ B2l,
    const float* __restrict__ bias, f16* __restrict__ C) {
    constexpr int HB = 8192;   // halves per 16KB sub-buffer ([256 rows][32 k])
    __shared__ __align__(16) f16 lds[9 * HB];   // AHx3 | ALx2 | BHx2 | BLx2

    const int t = threadIdx.x;
    const int m0 = blockIdx.x * 256;
    const int lane = t & 63;
    const int wid = t >> 6;        // 0..7
    const int wr = wid >> 1;       // 0..3 : 64-row band
    const int wc = wid & 1;        // 0..1 : 128-col band
    const int l31 = lane & 31;
    const int kg = lane >> 5;      // 0..1 : k-group within 16-k slice

    // staging geometry: lane -> (row 0..127, inverse-swizzled 8-half chunk).
    // VERIFIED swizzle form: chunk ^ ((row>>1)&3).
    const int srow = wid * 16 + (lane >> 2);
    const int sko = ((lane & 3) ^ ((srow >> 1) & 3)) * 8;

    f32x16 acc[2][4];
#pragma unroll
    for (int a = 0; a < 2; a++)
#pragma unroll
        for (int b = 0; b < 4; b++)
#pragma unroll
            for (int i = 0; i < 16; i++) acc[a][b][i] = 0.f;

    constexpr int NMAT = HAS_A2 ? 2 : 1;
    constexpr int NST = (K / 32) * NMAT;

#define SRC_DECL(S)                                                            \
    const int mat_ = HAS_A2 ? ((S) & 1) : 0;                                   \
    const int kb_ = (HAS_A2 ? ((S) >> 1) : (S)) * 32;

#define ISSUE_AH(S)                                                            \
    {                                                                          \
        SRC_DECL(S)                                                            \
        const f16* A_ = (mat_ == 0) ? A1 : A2;                                 \
        f16* dst_ = lds + ((S) % 3) * HB + wid * 512;                          \
        dma16(A_ + (size_t)(m0 + srow) * (2 * K) + kb_ + sko, dst_);           \
        dma16(A_ + (size_t)(m0 + srow + 128) * (2 * K) + kb_ + sko, dst_ + 4096); \
    }
#define ISSUE_AL(S)                                                            \
    {                                                                          \
        SRC_DECL(S)                                                            \
        const f16* A_ = (mat_ == 0) ? A1 : A2;                                 \
        f16* dst_ = lds + (3 + ((S) & 1)) * HB + wid * 512;                    \
        dma16(A_ + (size_t)(m0 + srow) * (2 * K) + K + kb_ + sko, dst_);       \
        dma16(A_ + (size_t)(m0 + srow + 128) * (2 * K) + K + kb_ + sko, dst_ + 4096); \
    }
#define ISSUE_BH(S)                                                            \
    {                                                                          \
        SRC_DECL(S)                                                            \
        const f16* B_ = (mat_ == 0) ? B1h : B2h;                               \
        f16* dst_ = lds + (5 + ((S) & 1)) * HB + wid * 512;                    \
        dma16(B_ + (size_t)srow * K + kb_ + sko, dst_);                        \
        dma16(B_ + (size_t)(srow + 128) * K + kb_ + sko, dst_ + 4096);         \
    }
#define ISSUE_BL(S)                                                            \
    {                                                                          \
        SRC_DECL(S)                                                            \
        const f16* B_ = (mat_ == 0) ? B1l : B2l;                               \
        f16* dst_ = lds + (7 + ((S) & 1)) * HB + wid * 512;                    \
        dma16(B_ + (size_t)srow * K + kb_ + sko, dst_);                        \
        dma16(B_ + (size_t)(srow + 128) * K + kb_ + sko, dst_ + 4096);         \
    }

#define MFMA32(D, X, Y) D = __builtin_amdgcn_mfma_f32_32x32x16_f16(X, Y, D, 0, 0, 0)

    // ---- prologue: stage 0 full + AH(1); AH last so vmcnt(2) spares it ----
    ISSUE_AH(0);
    ISSUE_AL(0);
    ISSUE_BH(0);
    ISSUE_BL(0);
    if (NST > 1) {
        ISSUE_AH(1);
        asm volatile("s_waitcnt vmcnt(2)" ::: "memory");
    } else {
        asm volatile("s_waitcnt vmcnt(0)" ::: "memory");
    }
    __builtin_amdgcn_s_barrier();
    __builtin_amdgcn_sched_barrier(0);

#pragma unroll
    for (int s = 0; s < NST; s++) {
        // issue next-stage loads (AL/BH/BL depth-1, AH depth-2, AH LAST)
        if (s + 1 < NST) { ISSUE_AL(s + 1); ISSUE_BH(s + 1); ISSUE_BL(s + 1); }
        if (s + 2 < NST) { ISSUE_AH(s + 2); }

        const f16* pAH = lds + (s % 3) * HB;
        const f16* pAL = lds + (3 + (s & 1)) * HB;
        const f16* pBH = lds + (5 + (s & 1)) * HB;
        const f16* pBL = lds + (7 + (s & 1)) * HB;

#pragma unroll
        for (int ks = 0; ks < 2; ks++) {
            f16x8 ah[2], ahq[2], al[2], alq[2], bh[4], bl[4];
#pragma unroll
            for (int mt = 0; mt < 2; mt++) {
                const int r = wr * 64 + mt * 32 + l31;
                const int ad = r * 32 + ((((ks << 1) | kg) ^ ((r >> 1) & 3)) << 3);
                ah[mt] = *(const f16x8*)(pAH + ad);
                al[mt] = *(const f16x8*)(pAL + ad);
                ahq[mt] = ah[mt] * (f16)INV_LO;
                alq[mt] = al[mt] * (f16)INV_LO;
            }
#pragma unroll
            for (int nt = 0; nt < 4; nt++) {
                const int r = wc * 128 + nt * 32 + l31;
                const int ad = r * 32 + ((((ks << 1) | kg) ^ ((r >> 1) & 3)) << 3);
                bh[nt] = *(const f16x8*)(pBH + ad);
                bl[nt] = *(const f16x8*)(pBL + ad);
            }
            // P1: xh*wh
#pragma unroll
            for (int nt = 0; nt < 4; nt++)
#pragma unroll
                for (int mt = 0; mt < 2; mt++) MFMA32(acc[mt][nt], ah[mt], bh[nt]);
            // P2: (xh/64)*wl'  (wl' stored = (W-wh)*64)
#pragma unroll
            for (int nt = 0; nt < 4; nt++)
#pragma unroll
                for (int mt = 0; mt < 2; mt++) MFMA32(acc[mt][nt], ahq[mt], bl[nt]);
            // P3: (xl'/64)*wh  (xl' stored = (x-xh)*64; == xl*(wh/64))
#pragma unroll
            for (int nt = 0; nt < 4; nt++)
#pragma unroll
                for (int mt = 0; mt < 2; mt++) MFMA32(acc[mt][nt], alq[mt], bh[nt]);
        }

        if (s + 1 < NST) {
            // drain own LDS reads (buffer-reuse safety), then counted vmcnt:
            // require AL/BH/BL(s+1) + AH(s+1) retired; allow AH(s+2) (2 newest).
            asm volatile("s_waitcnt lgkmcnt(0)" ::: "memory");
            if (s + 2 < NST) { asm volatile("s_waitcnt vmcnt(2)" ::: "memory"); }
            else             { asm volatile("s_waitcnt vmcnt(0)" ::: "memory"); }
            __builtin_amdgcn_s_barrier();
            __builtin_amdgcn_sched_barrier(0);
        }
    }
#undef SRC_DECL
#undef ISSUE_AH
#undef ISSUE_AL
#undef ISSUE_BH
#undef ISSUE_BL
#undef MFMA32

    // epilogue: 32x32 C/D layout: col = lane&31,
    // row = 4*(lane>>5) + (reg&3) + 8*(reg>>2)   [m74/m101 verified]
#pragma unroll
    for (int mt = 0; mt < 2; mt++) {
#pragma unroll
        for (int nt = 0; nt < 4; nt++) {
            const int col = wc * 128 + nt * 32 + l31;
            const float bv = bias[col];
#pragma unroll
            for (int reg = 0; reg < 16; reg++) {
                const int row = m0 + wr * 64 + mt * 32 + 4 * kg + (reg & 3) + 8 * (reg >> 2);
                float v = acc[mt][nt][reg] + bv;
                if (RELU) v = fmaxf(v, 0.f);
                f16 hi, lo;
                split2(v, hi, lo);
                C[(size_t)row * HSTR + col] = hi;
                C[(size_t)row * HSTR + HIDDIM + col] = lo;
            }
        }
    }
}

// ---------------------------------------------------------------------------
// Segment-mean of interleaved final h -> G[6000][256] fp32.
__global__ void readout_mean_kernel(const f16* __restrict__ H,
                                    const int* __restrict__ scopes, float* __restrict__ G) {
    int g = blockIdx.x;
    int n = threadIdx.x;
    int start = scopes[g * 2 + 0];
    int len = scopes[g * 2 + 1];
    float s = 0.f;
    for (int j = 0; j < len; j++) {
        const f16* row = H + (size_t)(start + j) * HSTR;
        s += (float)row[n] + (float)row[HIDDIM + n] * INV_LO;
    }
    int d = len > 1 ? len : 1;
    G[(size_t)g * HIDDIM + n] = s / (float)d;
}

// ---------------------------------------------------------------------------
// Tiny fp32 GEMM: out[g][n] = G[g][:] . W_out[n][:] + b_out[n], g<6000.
__global__ __launch_bounds__(256) void out_gemm_kernel(
    const float* __restrict__ G, const float* __restrict__ W,
    const float* __restrict__ bias, float* __restrict__ out) {
    __shared__ float sG[16 * 256];
    const int g0 = blockIdx.x * 16;
    const int t = threadIdx.x;
#pragma unroll
    for (int i = 0; i < 16; i++) sG[i * 256 + t] = G[(size_t)(g0 + i) * 256 + t];
    __syncthreads();
    const float bv = bias[t];
    const float* wrow = W + (size_t)t * 256;   // W[n][k] row-major
    float acc[16];
#pragma unroll
    for (int g = 0; g < 16; g++) acc[g] = 0.f;
    for (int k = 0; k < 256; k += 4) {
        const float4 w = *(const float4*)(wrow + k);
#pragma unroll
        for (int g = 0; g < 16; g++) {
            const float4 a = *(const float4*)(sG + g * 256 + k);   // broadcast
            acc[g] = fmaf(a.x, w.x, acc[g]);
            acc[g] = fmaf(a.y, w.y, acc[g]);
            acc[g] = fmaf(a.z, w.z, acc[g]);
            acc[g] = fmaf(a.w, w.w, acc[g]);
        }
    }
#pragma unroll
    for (int g = 0; g < 16; g++) out[(size_t)(g0 + g) * 256 + t] = acc[g] + bv;
}

// ---------------------------------------------------------------------------
extern "C" void kernel_launch(void* const* d_in, const int* in_sizes, int n_in,
                              void* d_out, int out_size, void* d_ws, size_t ws_size,
                              hipStream_t stream) {
    const int* a_features = (const int*)d_in[0];
    const int* b_features = (const int*)d_in[1];
    const int* a_scopes   = (const int*)d_in[2];
    const float* emb      = (const float*)d_in[3];
    const float* W_in     = (const float*)d_in[4];
    const float* b_in     = (const float*)d_in[5];
    const float* W_self   = (const float*)d_in[6];
    const float* b_self   = (const float*)d_in[7];
    const float* W_neigh  = (const float*)d_in[8];
    const float* b_neigh  = (const float*)d_in[9];
    const float* W_out    = (const float*)d_in[10];
    const float* b_out    = (const float*)d_in[11];

    if (g_pool == nullptr) {
        fill_kernel<<<(out_size + 255) / 256, 256, 0, stream>>>(
            (float*)d_out, 77777.0f, out_size);
        return;
    }

    // ---- pool layout (halves); interleaved h buffers [hi256|lo256] ----
    f16* p = (f16*)g_pool;
    const size_t HB2 = (size_t)MP * HSTR;        // 153,616,384 halves / buffer
    f16* bufA = p;
    f16* bufB = p + HB2;
    f16* bufC = p + 2 * HB2;
    f16* xbuf = p + 3 * HB2;                     // [MP][64] interleaved
    f16* Winh = xbuf + (size_t)MP * XSTR;
    f16* Winl = Winh + HIDDIM * DCOL;
    f16* Wsh  = Winl + HIDDIM * DCOL;
    f16* Wsl  = Wsh + HIDDIM * HIDDIM;
    f16* Wnh  = Wsl + HIDDIM * HIDDIM;
    f16* Wnl  = Wnh + HIDDIM * HIDDIM;
    float* Gmean = (float*)(Wnl + HIDDIM * HIDDIM);        // [6000][256] fp32
    float* bsum  = Gmean + (size_t)NGRAPHS * HIDDIM;
    int* csr = (int*)(bsum + HIDDIM);            // [MP][ECAP]
    int* cnt = csr + (size_t)MP * ECAP;          // [MP]

    constexpr int NPAD = MP - NATOMS;            // 32 pad rows

    // ---- setup (identical every launch) ----
    hipMemsetAsync(cnt, 0, (size_t)MP * sizeof(int), stream);
    csr_build_kernel<<<(2 * NBONDS + 255) / 256, 256, 0, stream>>>(b_features, cnt, csr);
    wsplit_kernel<<<(HIDDIM * DCOL + 255) / 256, 256, 0, stream>>>(W_in, Winh, Winl, HIDDIM * DCOL);
    wsplit_kernel<<<(HIDDIM * HIDDIM + 255) / 256, 256, 0, stream>>>(W_self, Wsh, Wsl, HIDDIM * HIDDIM);
    wsplit_kernel<<<(HIDDIM * HIDDIM + 255) / 256, 256, 0, stream>>>(W_neigh, Wnh, Wnl, HIDDIM * HIDDIM);
    bsum_kernel<<<1, HIDDIM, 0, stream>>>(b_self, b_neigh, bsum);

    // Zero padding rows (pool is persistent; keeps pad lanes deterministic).
    constexpr int PADH = NPAD * HSTR / 2;        // halves -> floats
    fill_kernel<<<(PADH + 255) / 256, 256, 0, stream>>>((float*)(bufA + (size_t)NATOMS * HSTR), 0.f, PADH);
    fill_kernel<<<(PADH + 255) / 256, 256, 0, stream>>>((float*)(bufB + (size_t)NATOMS * HSTR), 0.f, PADH);
    fill_kernel<<<(PADH + 255) / 256, 256, 0, stream>>>((float*)(bufC + (size_t)NATOMS * HSTR), 0.f, PADH);
    constexpr int PADX = NPAD * XSTR / 2;
    fill_kernel<<<(PADX + 255) / 256, 256, 0, stream>>>((float*)(xbuf + (size_t)NATOMS * XSTR), 0.f, PADX);

    // ---- embedding + input linear -> h (bufA) ----
    embed_kernel<<<(NATOMS * DCOL + 255) / 256, 256, 0, stream>>>(a_features, emb, xbuf);
    mfma_gemm<false, false, DCOL><<<MTILES256, 512, 0, stream>>>(
        xbuf, nullptr, Winh, Winl, nullptr, nullptr, b_in, bufA);

    // ---- 3 message-passing steps with rotating buffers ----
    f16* h  = bufA;
    f16* g  = bufB;
    f16* hn = bufC;
    for (int s = 0; s < NSTEPS; s++) {
        agg_kernel<<<NATOMS / 4, 256, 0, stream>>>(h, g, cnt, csr);
        mfma_gemm<true, true, HIDDIM><<<MTILES256, 512, 0, stream>>>(
            h, g, Wsh, Wsl, Wnh, Wnl, bsum, hn);
        f16* old = h;
        h = hn; hn = g; g = old;
    }

    // ---- mean first (linearity), then tiny output linear ----
    readout_mean_kernel<<<NGRAPHS, 256, 0, stream>>>(h, a_scopes, Gmean);
    out_gemm_kernel<<<NGRAPHS / 16, 256, 0, stream>>>(Gmean, W_out, b_out, (float*)d_out);
}